// Round 2
// baseline (5193.069 us; speedup 1.0000x reference)
//
#include <hip/hip_runtime.h>
#include <math.h>

#define B_    2
#define N_    4096
#define BN_   (B_*N_)
#define H0    480
#define W0    640
#define FH_   240
#define FW_   320
#define PIX_  (B_*FH_*FW_)     // 153600
#define KNN_K 20
#define CH_   16               // candidate chunks per KNN
#define CHSZ  (N_/CH_)         // 256

// ---------------- workspace layout (float offsets) ----------------
static const size_t OFF_RS   = 0;                       // 2880
static const size_t OFF_CS   = 2944;                    // 3840
static const size_t OFF_PH   = 6784;                    // 23040
static const size_t OFF_PW   = 29824;                   // 30720
static const size_t OFF_Y8   = 60544;                   // 17920
static const size_t OFF_AH   = 78464;                   // 23040
static const size_t OFF_AW   = 101504;                  // 30720
static const size_t OFF_VB   = 132224;                  // 8192 (int)
static const size_t OFF_UB   = 140416;                  // 8192 (int)
static const size_t OFF_F3D  = 148608;                  // 262144
static const size_t OFF_XX   = 410752;                  // 8192
static const size_t OFF_PV   = 418944;                  // 2621440
static const size_t OFF_PI   = 3040384;                 // 2621440 (int)
static const size_t OFF_IDX  = 5661824;                 // 163840 (int)
static const size_t OFF_X1   = 5825664;                 // 524288
static const size_t OFF_X2   = 6349952;                 // 524288
static const size_t OFF_X3   = 6874240;                 // 1048576
static const size_t OFF_T1   = 7922816;                 // 4096
static const size_t OFF_T2   = 7926912;                 // 8192
static const size_t OFF_T3   = 7935104;                 // 16384
static const size_t OFF_T7A  = 7951488;                 // 4096
static const size_t OFF_T7B  = 7955584;                 // 8192
static const size_t OFF_FMA  = 7963776;                 // 9830400  (pd matrix reuses fmA+fmV during KNN)
static const size_t OFF_FMV  = 17794176;                // 9830400
static const size_t OFF_FMB  = 27624576;                // 9830400

// ---------------- small weight transposes ----------------
__global__ void k_transpose(const float* __restrict__ w1, const float* __restrict__ w2,
                            const float* __restrict__ w3, const float* __restrict__ w7a,
                            const float* __restrict__ w7b,
                            float* __restrict__ t1, float* __restrict__ t2,
                            float* __restrict__ t3, float* __restrict__ t7a,
                            float* __restrict__ t7b) {
    int t = blockIdx.x * 256 + threadIdx.x;
    if (t < 4096) {                         // conv1 (64,64) -> [i*64+o]
        int i = t >> 6, o = t & 63; t1[i*64+o] = w1[o*64+i];
    } else if (t < 12288) {                 // conv2 (64,128) -> [i*64+o], i<128
        int r = t - 4096; int i = r >> 6, o = r & 63; t2[i*64+o] = w2[o*128+i];
    } else if (t < 28672) {                 // conv3 (128,128) -> [i*128+o]
        int r = t - 12288; int i = r >> 7, o = r & 127; t3[i*128+o] = w3[o*128+i];
    } else if (t < 32768) {                 // conv7a (64,64) -> [c*64+o]
        int r = t - 28672; int c = r >> 6, o = r & 63; t7a[c*64+o] = w7a[o*64+c];
    } else if (t < 40960) {                 // conv7b (128,64) -> [o*128+p]
        int r = t - 32768; int o = r >> 7, p = r & 127; t7b[o*128+p] = w7b[p*64+o];
    }
}

// ---------------- input row/col sums ----------------
__global__ void k_colsum(const float* __restrict__ img, float* __restrict__ cs) {
    int bc = blockIdx.x; int x = threadIdx.x;   // grid 6, block 640
    const float* p = img + (size_t)bc * H0 * W0;
    float acc = 0.f;
    for (int h = 0; h < H0; ++h) acc += p[h * W0 + x];
    cs[bc * W0 + x] = acc;
}
__global__ void k_rowsum(const float* __restrict__ img, float* __restrict__ rs) {
    int bc = blockIdx.x; int y = threadIdx.x;   // grid 6, block 480
    const float* p = img + (size_t)bc * H0 * W0 + (size_t)y * W0;
    float acc = 0.f;
    for (int x = 0; x < W0; ++x) acc += p[x];
    rs[bc * H0 + y] = acc;
}

// ---------------- pooled conv means ph/pw ----------------
__global__ void k_ph(const float* __restrict__ img, const float* __restrict__ rs,
                     const float* __restrict__ w, const float* __restrict__ bias,
                     float* __restrict__ ph) {
    int t = blockIdx.x * 256 + threadIdx.x;
    if (t >= B_ * 24 * H0) return;
    int h = t % H0; int bc = t / H0; int c = bc % 24; int b = bc / 24;
    float acc = 0.f;
    for (int ic = 0; ic < 3; ++ic)
        for (int dy = 0; dy < 3; ++dy) {
            int y = h + dy - 1;
            if ((unsigned)y >= (unsigned)H0) continue;
            float r = rs[(b*3+ic)*H0 + y];
            const float* row = img + (size_t)((b*3+ic)*H0 + y) * W0;
            float e0 = row[0], eL = row[W0-1];
            const float* wp = w + ((c*3+ic)*3+dy)*3;
            acc += wp[0]*(r - eL) + wp[1]*r + wp[2]*(r - e0);
        }
    ph[t] = bias[c] + acc / 640.0f;
}
__global__ void k_pw(const float* __restrict__ img, const float* __restrict__ cs,
                     const float* __restrict__ w, const float* __restrict__ bias,
                     float* __restrict__ pw) {
    int t = blockIdx.x * 256 + threadIdx.x;
    if (t >= B_ * 24 * W0) return;
    int x = t % W0; int bc = t / W0; int c = bc % 24; int b = bc / 24;
    float acc = 0.f;
    for (int ic = 0; ic < 3; ++ic)
        for (int dx = 0; dx < 3; ++dx) {
            int xx = x + dx - 1;
            if ((unsigned)xx >= (unsigned)W0) continue;
            float csv = cs[(b*3+ic)*W0 + xx];
            const float* base = img + (size_t)(b*3+ic) * H0 * W0;
            float top = base[xx];                   // h=0
            float bot = base[(size_t)(H0-1)*W0 + xx];
            const float* wp = w + ((c*3+ic)*3)*3 + dx;
            acc += wp[0]*(csv - bot) + wp[3]*csv + wp[6]*(csv - top);
        }
    pw[t] = bias[c] + acc / 480.0f;
}

// ---------------- coord-attention mid + gates ----------------
__global__ void k_y8(const float* __restrict__ ph, const float* __restrict__ pw,
                     const float* __restrict__ c1w, const float* __restrict__ c1b,
                     const float* __restrict__ bnp, float* __restrict__ y8) {
    int t = blockIdx.x * 256 + threadIdx.x;
    if (t >= B_ * 8 * 1120) return;
    int pos = t % 1120; int bj = t / 1120; int j = bj % 8; int b = bj / 8;
    float s = c1b[j];
    for (int c = 0; c < 24; ++c) {
        float yv = (pos < H0) ? ph[(b*24+c)*H0 + pos] : pw[(b*24+c)*W0 + (pos - H0)];
        s = fmaf(c1w[j*24+c], yv, s);
    }
    float g = bnp[j], be = bnp[8+j], m = bnp[16+j], va = bnp[24+j];
    float v = (s - m) * (g / sqrtf(va + 1e-5f)) + be;
    float hs = v * fminf(fmaxf(v + 3.f, 0.f), 6.f) * (1.f/6.f);
    y8[(b*8+j)*1120 + pos] = hs;
}
__global__ void k_ahw(const float* __restrict__ y8,
                      const float* __restrict__ chw, const float* __restrict__ chb,
                      const float* __restrict__ cww, const float* __restrict__ cwb,
                      float* __restrict__ ah, float* __restrict__ aw) {
    int t = blockIdx.x * 256 + threadIdx.x;
    if (t >= B_ * 24 * 1120) return;
    int pos = t % 1120; int bc = t / 1120; int c = bc % 24; int b = bc / 24;
    if (pos < H0) {
        float s = chb[c];
        for (int j = 0; j < 8; ++j) s = fmaf(chw[c*8+j], y8[(b*8+j)*1120 + pos], s);
        ah[(b*24+c)*H0 + pos] = 1.f / (1.f + expf(-s));
    } else {
        float s = cwb[c];
        for (int j = 0; j < 8; ++j) s = fmaf(cww[c*8+j], y8[(b*8+j)*1120 + pos], s);
        aw[(b*24+c)*W0 + (pos - H0)] = 1.f / (1.f + expf(-s));
    }
}

// ---------------- feat3d gather (+v/u + idx output) ----------------
__global__ void k_feat3d(const float* __restrict__ pc, const float* __restrict__ img,
                         const float* __restrict__ w, const float* __restrict__ bias,
                         const float* __restrict__ ah, const float* __restrict__ aw,
                         float* __restrict__ f3d, int* __restrict__ vbuf,
                         int* __restrict__ ubuf, float* __restrict__ idx_out) {
    int t = blockIdx.x * 256 + threadIdx.x;
    if (t >= BN_ * 32) return;
    int c = t & 31; int bn = t >> 5; int b = bn >> 12; int n = bn & (N_-1);
    float pv = pc[(b*8 + 0)*N_ + n];
    float pu = pc[(b*8 + 1)*N_ + n];
    int v = (int)floorf(pv + 240.f);
    int u = (int)floorf(pu + 320.f);
    float f;
    if (c < 8) {
        f = pc[(b*8 + c)*N_ + n];
    } else {
        int co = c - 8;
        float acc = bias[co];
        for (int ic = 0; ic < 3; ++ic)
            for (int dy = 0; dy < 3; ++dy) {
                int y = v + dy - 1;
                if ((unsigned)y >= (unsigned)H0) continue;
                for (int dx = 0; dx < 3; ++dx) {
                    int x = u + dx - 1;
                    if ((unsigned)x >= (unsigned)W0) continue;
                    acc = fmaf(w[((co*3+ic)*3+dy)*3+dx],
                               img[((size_t)(b*3+ic)*H0 + y)*W0 + x], acc);
                }
            }
        f = acc * ah[(b*24+co)*H0 + v] * aw[(b*24+co)*W0 + u];
    }
    f3d[(size_t)bn*32 + c] = f;
    if (c == 0) {
        vbuf[bn] = v; ubuf[bn] = u;
        idx_out[bn] = (float)b;
        idx_out[BN_ + bn] = (float)(v >> 1);
        idx_out[2*BN_ + bn] = (float)(u >> 1);
    }
}

// ---------------- squared norms ----------------
template<int C>
__global__ void k_sqnorm(const float* __restrict__ X, float* __restrict__ XX) {
    int t = blockIdx.x * 256 + threadIdx.x;
    if (t >= BN_) return;
    float acc = 0.f;
    const float* p = X + (size_t)t * C;
#pragma unroll
    for (int i = 0; i < C; ++i) acc = fmaf(p[i], p[i], acc);
    XX[t] = acc;
}

// ---------------- distance matrix: pd[c][q] = 2<xc,xq> - |xc|^2 - |xq|^2 ----
// 64x64 tile per block, 4x4 per thread, one batch per launch.
template<int C>
__launch_bounds__(256)
__global__ void k_dist(const float* __restrict__ X, const float* __restrict__ XX,
                       float* __restrict__ pd, int b) {
    __shared__ float As[C][64];   // queries  (rows of output tile)
    __shared__ float Bs[C][64];   // columns
    int bi = blockIdx.x;
    int I = bi >> 6, J = bi & 63;
    int tid = threadIdx.x;
    {   // stage: thread t loads C/4 contiguous floats of row (t/4) for A and B
        int r = tid >> 2;
        int kc0 = (tid & 3) * (C / 4);
        const float* qa = X + ((size_t)(b * N_ + I * 64 + r)) * C + kc0;
        const float* ca = X + ((size_t)(b * N_ + J * 64 + r)) * C + kc0;
#pragma unroll
        for (int i4 = 0; i4 < C / 16; ++i4) {
            float4 va = *(const float4*)(qa + i4 * 4);
            float4 vb = *(const float4*)(ca + i4 * 4);
            int k = kc0 + i4 * 4;
            As[k+0][r] = va.x; As[k+1][r] = va.y; As[k+2][r] = va.z; As[k+3][r] = va.w;
            Bs[k+0][r] = vb.x; Bs[k+1][r] = vb.y; Bs[k+2][r] = vb.z; Bs[k+3][r] = vb.w;
        }
    }
    __syncthreads();
    int tx = tid & 15, ty = tid >> 4;
    float acc[4][4] = {{0.f}};
#pragma unroll
    for (int k = 0; k < C; ++k) {
        float4 a4 = *(const float4*)&As[k][ty * 4];
        float4 b4 = *(const float4*)&Bs[k][tx * 4];
        float av[4] = {a4.x, a4.y, a4.z, a4.w};
        float bv[4] = {b4.x, b4.y, b4.z, b4.w};
#pragma unroll
        for (int i = 0; i < 4; ++i)
#pragma unroll
            for (int j = 0; j < 4; ++j)
                acc[i][j] = fmaf(av[i], bv[j], acc[i][j]);
    }
    float xq[4], xc[4];
#pragma unroll
    for (int i = 0; i < 4; ++i) {
        xq[i] = XX[b * N_ + I * 64 + ty * 4 + i];
        xc[i] = XX[b * N_ + J * 64 + tx * 4 + i];
    }
#pragma unroll
    for (int i = 0; i < 4; ++i) {
        float4 o;
        o.x = 2.f * acc[i][0] - xq[i] - xc[0];
        o.y = 2.f * acc[i][1] - xq[i] - xc[1];
        o.z = 2.f * acc[i][2] - xq[i] - xc[2];
        o.w = 2.f * acc[i][3] - xq[i] - xc[3];
        *(float4*)&pd[(size_t)(I * 64 + ty * 4 + i) * N_ + J * 64 + tx * 4] = o;
    }
}

// ---------------- chunked top-20 scan of materialized pd ----------------
// pd is symmetric: read pd[c*N+q] so lanes (consecutive q) are coalesced.
__launch_bounds__(256)
__global__ void k_select(const float* __restrict__ pd, float* __restrict__ pV,
                         int* __restrict__ pI, int b) {
    int bid = blockIdx.x;                    // (N/256)*CH blocks
    int ch = bid & (CH_-1); int qt = bid >> 4;
    int q = qt * 256 + threadIdx.x;
    float val[KNN_K]; int idx[KNN_K];
#pragma unroll
    for (int j = 0; j < KNN_K; ++j) { val[j] = -INFINITY; idx[j] = -1; }
    int cbase = ch * CHSZ;
    for (int t = 0; t < CHSZ; ++t) {
        int c = cbase + t;
        float v = pd[(size_t)c * N_ + q];
        if (v > val[KNN_K-1]) {
            float cv = v; int ci = c; bool ins = false;
#pragma unroll
            for (int j = 0; j < KNN_K; ++j) {
                bool sw = ins || (cv > val[j]);
                if (sw) {
                    float tv = val[j]; val[j] = cv; cv = tv;
                    int ti = idx[j]; idx[j] = ci; ci = ti;
                    ins = true;
                }
            }
        }
    }
    size_t base = (((size_t)b * N_ + q) * CH_ + ch) * KNN_K;
#pragma unroll
    for (int j = 0; j < KNN_K; ++j) { pV[base + j] = val[j]; pI[base + j] = idx[j]; }
}

__global__ void k_merge(const float* __restrict__ pV, const int* __restrict__ pI,
                        int* __restrict__ idxb) {
    int t = blockIdx.x * 256 + threadIdx.x;   // grid 32
    __shared__ int sh[CH_ * 256];
    for (int ch = 0; ch < CH_; ++ch) sh[ch*256 + threadIdx.x] = 0;
    size_t base = (size_t)t * CH_ * KNN_K;
    for (int slot = 0; slot < KNN_K; ++slot) {
        float best = -INFINITY; int bc = 0;
        for (int ch = 0; ch < CH_; ++ch) {
            int hd = sh[ch*256 + threadIdx.x];
            if (hd < KNN_K) {
                float v = pV[base + (size_t)ch*KNN_K + hd];
                if (v > best) { best = v; bc = ch; }
            }
        }
        int hd = sh[bc*256 + threadIdx.x];
        sh[bc*256 + threadIdx.x] = hd + 1;
        idxb[(size_t)t * KNN_K + slot] = pI[base + (size_t)bc*KNN_K + hd];
    }
}

// ---------------- EdgeConv: gather + 1x1 conv + bn + lrelu + max_k ----------------
template<int CIN, int COUT, int P>   // P*COUT == 256
__launch_bounds__(256)
__global__ void edgeconv(const float* __restrict__ X, const int* __restrict__ idxb,
                         const float* __restrict__ wT, const float* __restrict__ bnp,
                         float* __restrict__ Y) {
    __shared__ float sctr[P][CIN];
    __shared__ float snb[P][KNN_K * CIN];
    int base = blockIdx.x * P;
    int tid = threadIdx.x;
    for (int j = tid; j < P * CIN; j += 256) {
        int p = j / CIN, i = j % CIN;
        sctr[p][i] = X[(size_t)(base + p) * CIN + i];
    }
    for (int j = tid; j < P * KNN_K * CIN; j += 256) {
        int p = j / (KNN_K * CIN); int r = j % (KNN_K * CIN);
        int k = r / CIN; int i = r % CIN;
        int b = (base + p) / N_;
        int ni = idxb[(size_t)(base + p) * KNN_K + k];
        snb[p][k * CIN + i] = X[((size_t)b * N_ + ni) * CIN + i];
    }
    __syncthreads();
    int p = tid / COUT, o = tid % COUT;
    float g = bnp[o], bb = bnp[COUT + o], m = bnp[2*COUT + o], va = bnp[3*COUT + o];
    float a = g / sqrtf(va + 1e-5f);
    float sh = bb - m * a;
    float accc = 0.f;
#pragma unroll
    for (int i = 0; i < CIN; ++i)
        accc = fmaf(wT[(CIN + i) * COUT + o] - wT[i * COUT + o], sctr[p][i], accc);
    float mx = -INFINITY;
    for (int k = 0; k < KNN_K; ++k) {
        float s = accc;
#pragma unroll
        for (int i = 0; i < CIN; ++i)
            s = fmaf(wT[i * COUT + o], snb[p][k * CIN + i], s);
        float r = fmaf(s, a, sh);
        r = (r >= 0.f) ? r : 0.2f * r;
        mx = fmaxf(mx, r);
    }
    Y[(size_t)(base + p) * COUT + o] = mx;
}

// ---------------- lin4 (256->256->64) + scatter-add ----------------
__launch_bounds__(256)
__global__ void k_lin4(const float* __restrict__ x1, const float* __restrict__ x2,
                       const float* __restrict__ x3, const float* __restrict__ l4a,
                       const float* __restrict__ l4b, const int* __restrict__ vbuf,
                       const int* __restrict__ ubuf, float* __restrict__ fmA) {
    int bn = blockIdx.x; int tid = threadIdx.x;
    __shared__ float xc[256]; __shared__ float t1[256];
    if (tid < 64)        xc[tid] = x1[(size_t)bn*64 + tid];
    else if (tid < 128)  xc[tid] = x2[(size_t)bn*64 + tid - 64];
    else                 xc[tid] = x3[(size_t)bn*128 + tid - 128];
    __syncthreads();
    float acc = 0.f;
    for (int i = 0; i < 256; ++i) acc = fmaf(xc[i], l4a[i*256 + tid], acc);
    t1[tid] = acc;
    __syncthreads();
    if (tid < 64) {
        float a2 = 0.f;
        for (int i = 0; i < 256; ++i) a2 = fmaf(t1[i], l4b[i*64 + tid], a2);
        int b = bn >> 12; int v = vbuf[bn] >> 1; int u = ubuf[bn] >> 1;
        atomicAdd(fmA + ((size_t)(b*FH_ + v)*FW_ + u)*64 + tid, a2);
    }
}

// ---------------- per-pixel channel softmax ----------------
__global__ void k_softmax(float* __restrict__ fm) {
    int pix = blockIdx.x * 4 + (threadIdx.x >> 6);
    int l = threadIdx.x & 63;
    float x = fm[(size_t)pix*64 + l];
    float m = x;
    for (int off = 32; off > 0; off >>= 1) m = fmaxf(m, __shfl_xor(m, off));
    float e = expf(x - m);
    float s = e;
    for (int off = 32; off > 0; off >>= 1) s += __shfl_xor(s, off);
    fm[(size_t)pix*64 + l] = e / s;
}

// ---------------- DCN value GEMV ----------------
__global__ void k_dcnval(const float* __restrict__ in, const float* __restrict__ vw,
                         const float* __restrict__ vb, float* __restrict__ val) {
    __shared__ float sx[256];
    int tid = threadIdx.x;
    size_t base = (size_t)blockIdx.x * 256;
    sx[tid] = in[base + tid];
    __syncthreads();
    int o = tid & 63; int grp = tid >> 6;
    const float* xr = sx + grp*64;
    float acc = vb[o];
    for (int i = 0; i < 64; ++i) acc = fmaf(xr[i], vw[i*64 + o], acc);
    val[base + tid] = acc;
}

// ---------------- DCN offsets + sampling + out-proj + bn + lrelu ----------------
__launch_bounds__(128)
__global__ void k_dcnsamp(const float* __restrict__ in, const float* __restrict__ val,
                          const float* __restrict__ ow, const float* __restrict__ ob,
                          const float* __restrict__ pwm, const float* __restrict__ pbm,
                          const float* __restrict__ bnp, float* __restrict__ out) {
    int pix = blockIdx.x; int tid = threadIdx.x;
    int b = pix / (FH_*FW_); int hw = pix % (FH_*FW_);
    int h = hw / FW_; int w = hw % FW_;
    __shared__ float sx[64]; __shared__ float som[108]; __shared__ float ss[64];
    if (tid < 64) sx[tid] = in[(size_t)pix*64 + tid];
    __syncthreads();
    if (tid < 108) {
        float a = ob[tid];
        for (int i = 0; i < 64; ++i) a = fmaf(sx[i], ow[i*108 + tid], a);
        som[tid] = a;
    }
    __syncthreads();
    if (tid < 64) {
        int g = tid >> 4;
        const float* vbase = val + (size_t)b * FH_ * FW_ * 64 + tid;
        float acc = 0.f;
        for (int k = 0; k < 9; ++k) {
            int kx = k % 3 - 1, ky = k / 3 - 1;
            float lx = (float)(w + kx) + som[g*27 + k*3 + 0];
            float ly = (float)(h + ky) + som[g*27 + k*3 + 1];
            float msk = som[g*27 + k*3 + 2];
            float x0f = floorf(lx), y0f = floorf(ly);
            float wx = lx - x0f, wy = ly - y0f;
            int x0 = (int)x0f, y0 = (int)y0f;
            float w00 = (1.f-wx)*(1.f-wy), w01 = wx*(1.f-wy);
            float w10 = (1.f-wx)*wy,       w11 = wx*wy;
            if ((unsigned)y0 < (unsigned)FH_ && (unsigned)x0 < (unsigned)FW_)
                acc = fmaf(msk*w00, vbase[((size_t)y0*FW_ + x0)*64], acc);
            if ((unsigned)y0 < (unsigned)FH_ && (unsigned)(x0+1) < (unsigned)FW_)
                acc = fmaf(msk*w01, vbase[((size_t)y0*FW_ + x0+1)*64], acc);
            if ((unsigned)(y0+1) < (unsigned)FH_ && (unsigned)x0 < (unsigned)FW_)
                acc = fmaf(msk*w10, vbase[((size_t)(y0+1)*FW_ + x0)*64], acc);
            if ((unsigned)(y0+1) < (unsigned)FH_ && (unsigned)(x0+1) < (unsigned)FW_)
                acc = fmaf(msk*w11, vbase[((size_t)(y0+1)*FW_ + x0+1)*64], acc);
        }
        ss[tid] = acc;
    }
    __syncthreads();
    if (tid < 64) {
        float a = pbm[tid];
        for (int i = 0; i < 64; ++i) a = fmaf(ss[i], pwm[i*64 + tid], a);
        float g = bnp[tid], be = bnp[64+tid], m = bnp[128+tid], va = bnp[192+tid];
        float sc = g / sqrtf(va + 1e-5f);
        float r = (a - m) * sc + be;
        out[(size_t)pix*64 + tid] = (r >= 0.f) ? r : 0.2f * r;
    }
}

// ---------------- conv7a + conv7b ----------------
__launch_bounds__(128)
__global__ void k_conv7(const float* __restrict__ in, const float* __restrict__ w7aT,
                        const float* __restrict__ w7bT, float* __restrict__ out) {
    int pix = blockIdx.x; int tid = threadIdx.x;
    int b = pix / (FH_*FW_); int hw = pix % (FH_*FW_);
    __shared__ float sx[64]; __shared__ float st[64];
    if (tid < 64) sx[tid] = in[(size_t)pix*64 + tid];
    __syncthreads();
    if (tid < 64) {
        float a = 0.f;
        for (int c = 0; c < 64; ++c) a = fmaf(sx[c], w7aT[c*64 + tid], a);
        st[tid] = a;
    }
    __syncthreads();
    float a = 0.f;
    for (int o = 0; o < 64; ++o) a = fmaf(st[o], w7bT[o*128 + tid], a);
    out[((size_t)b*128 + tid)*(FH_*FW_) + hw] = a;
}

// ---------------- launch ----------------
extern "C" void kernel_launch(void* const* d_in, const int* in_sizes, int n_in,
                              void* d_out, int out_size, void* d_ws, size_t ws_size,
                              hipStream_t stream) {
    (void)in_sizes; (void)n_in; (void)out_size; (void)ws_size;
    const float* pc   = (const float*)d_in[0];
    const float* img  = (const float*)d_in[1];
    const float* pcw  = (const float*)d_in[2];
    const float* pcb  = (const float*)d_in[3];
    const float* c1w  = (const float*)d_in[4];
    const float* c1b  = (const float*)d_in[5];
    const float* cabn = (const float*)d_in[6];
    const float* chw  = (const float*)d_in[7];
    const float* chb  = (const float*)d_in[8];
    const float* cww  = (const float*)d_in[9];
    const float* cwb  = (const float*)d_in[10];
    const float* w1   = (const float*)d_in[11];
    const float* bn1  = (const float*)d_in[12];
    const float* w2   = (const float*)d_in[13];
    const float* bn2  = (const float*)d_in[14];
    const float* w3   = (const float*)d_in[15];
    const float* bn3  = (const float*)d_in[16];
    const float* l4a  = (const float*)d_in[17];
    const float* l4b  = (const float*)d_in[18];
    const float* d5ow = (const float*)d_in[19];
    const float* d5ob = (const float*)d_in[20];
    const float* d5vw = (const float*)d_in[21];
    const float* d5vb = (const float*)d_in[22];
    const float* d5pw = (const float*)d_in[23];
    const float* d5pb = (const float*)d_in[24];
    const float* bn5  = (const float*)d_in[25];
    const float* d6ow = (const float*)d_in[26];
    const float* d6ob = (const float*)d_in[27];
    const float* d6vw = (const float*)d_in[28];
    const float* d6vb = (const float*)d_in[29];
    const float* d6pw = (const float*)d_in[30];
    const float* d6pb = (const float*)d_in[31];
    const float* bn6  = (const float*)d_in[32];
    const float* w7a  = (const float*)d_in[33];
    const float* w7b  = (const float*)d_in[34];

    float* ws  = (float*)d_ws;
    float* out = (float*)d_out;

    float* rs  = ws + OFF_RS;   float* cs  = ws + OFF_CS;
    float* ph  = ws + OFF_PH;   float* pw  = ws + OFF_PW;
    float* y8  = ws + OFF_Y8;   float* ah  = ws + OFF_AH;  float* aw = ws + OFF_AW;
    int*   vb  = (int*)(ws + OFF_VB);
    int*   ub  = (int*)(ws + OFF_UB);
    float* f3d = ws + OFF_F3D;  float* xx  = ws + OFF_XX;
    float* pV  = ws + OFF_PV;
    int*   pI  = (int*)(ws + OFF_PI);
    int*   idxb = (int*)(ws + OFF_IDX);
    float* x1  = ws + OFF_X1;   float* x2  = ws + OFF_X2;  float* x3 = ws + OFF_X3;
    float* t1  = ws + OFF_T1;   float* t2  = ws + OFF_T2;  float* t3 = ws + OFF_T3;
    float* t7a = ws + OFF_T7A;  float* t7b = ws + OFF_T7B;
    float* fmA = ws + OFF_FMA;  float* fmV = ws + OFF_FMV; float* fmB = ws + OFF_FMB;
    float* pdb = ws + OFF_FMA;  // pd matrix (67 MB) reuses fmA+fmV region during KNN

    k_transpose<<<160, 256, 0, stream>>>(w1, w2, w3, w7a, w7b, t1, t2, t3, t7a, t7b);
    k_colsum<<<B_*3, W0, 0, stream>>>(img, cs);
    k_rowsum<<<B_*3, H0, 0, stream>>>(img, rs);
    k_ph<<<(B_*24*H0 + 255)/256, 256, 0, stream>>>(img, rs, pcw, pcb, ph);
    k_pw<<<(B_*24*W0 + 255)/256, 256, 0, stream>>>(img, cs, pcw, pcb, pw);
    k_y8<<<(B_*8*1120 + 255)/256, 256, 0, stream>>>(ph, pw, c1w, c1b, cabn, y8);
    k_ahw<<<(B_*24*1120 + 255)/256, 256, 0, stream>>>(y8, chw, chb, cww, cwb, ah, aw);
    k_feat3d<<<(BN_*32)/256, 256, 0, stream>>>(pc, img, pcw, pcb, ah, aw, f3d, vb, ub,
                                               out + (size_t)B_*128*FH_*FW_);

    // EdgeConv stage 1 (C=32)
    k_sqnorm<32><<<BN_/256, 256, 0, stream>>>(f3d, xx);
    for (int b = 0; b < B_; ++b) {
        k_dist<32><<<4096, 256, 0, stream>>>(f3d, xx, pdb, b);
        k_select<<<256, 256, 0, stream>>>(pdb, pV, pI, b);
    }
    k_merge<<<BN_/256, 256, 0, stream>>>(pV, pI, idxb);
    edgeconv<32,64,4><<<BN_/4, 256, 0, stream>>>(f3d, idxb, t1, bn1, x1);
    // stage 2 (C=64)
    k_sqnorm<64><<<BN_/256, 256, 0, stream>>>(x1, xx);
    for (int b = 0; b < B_; ++b) {
        k_dist<64><<<4096, 256, 0, stream>>>(x1, xx, pdb, b);
        k_select<<<256, 256, 0, stream>>>(pdb, pV, pI, b);
    }
    k_merge<<<BN_/256, 256, 0, stream>>>(pV, pI, idxb);
    edgeconv<64,64,4><<<BN_/4, 256, 0, stream>>>(x1, idxb, t2, bn2, x2);
    // stage 3 (C=64)
    k_sqnorm<64><<<BN_/256, 256, 0, stream>>>(x2, xx);
    for (int b = 0; b < B_; ++b) {
        k_dist<64><<<4096, 256, 0, stream>>>(x2, xx, pdb, b);
        k_select<<<256, 256, 0, stream>>>(pdb, pV, pI, b);
    }
    k_merge<<<BN_/256, 256, 0, stream>>>(pV, pI, idxb);
    edgeconv<64,128,2><<<BN_/2, 256, 0, stream>>>(x2, idxb, t3, bn3, x3);

    // fm pipeline (fmA/fmV free again from here)
    hipMemsetAsync(fmA, 0, (size_t)PIX_ * 64 * sizeof(float), stream);
    k_lin4<<<BN_, 256, 0, stream>>>(x1, x2, x3, l4a, l4b, vb, ub, fmA);
    k_softmax<<<PIX_/4, 256, 0, stream>>>(fmA);

    k_dcnval<<<PIX_*64/256, 256, 0, stream>>>(fmA, d5vw, d5vb, fmV);
    k_dcnsamp<<<PIX_, 128, 0, stream>>>(fmA, fmV, d5ow, d5ob, d5pw, d5pb, bn5, fmB);
    k_dcnval<<<PIX_*64/256, 256, 0, stream>>>(fmB, d6vw, d6vb, fmV);
    k_dcnsamp<<<PIX_, 128, 0, stream>>>(fmB, fmV, d6ow, d6ob, d6pw, d6pb, bn6, fmA);

    k_conv7<<<PIX_, 128, 0, stream>>>(fmA, t7a, t7b, out);
}

// Round 3
// 2407.124 us; speedup vs baseline: 2.1574x; 2.1574x over previous
//
#include <hip/hip_runtime.h>
#include <math.h>

#define B_    2
#define N_    4096
#define BN_   (B_*N_)
#define H0    480
#define W0    640
#define FH_   240
#define FW_   320
#define PIX_  (B_*FH_*FW_)     // 153600
#define KNN_K 20

// ---------------- workspace layout (float offsets) ----------------
static const size_t OFF_RS   = 0;                       // 2880
static const size_t OFF_CS   = 2944;                    // 3840
static const size_t OFF_PH   = 6784;                    // 23040
static const size_t OFF_PW   = 29824;                   // 30720
static const size_t OFF_Y8   = 60544;                   // 17920
static const size_t OFF_AH   = 78464;                   // 23040
static const size_t OFF_AW   = 101504;                  // 30720
static const size_t OFF_VB   = 132224;                  // 8192 (int)
static const size_t OFF_UB   = 140416;                  // 8192 (int)
static const size_t OFF_F3D  = 148608;                  // 262144
static const size_t OFF_XX   = 410752;                  // 8192
static const size_t OFF_IDX  = 5661824;                 // 163840 (int)
static const size_t OFF_X1   = 5825664;                 // 524288
static const size_t OFF_X2   = 6349952;                 // 524288
static const size_t OFF_X3   = 6874240;                 // 1048576
static const size_t OFF_T1   = 7922816;                 // 4096
static const size_t OFF_T2   = 7926912;                 // 8192
static const size_t OFF_T3   = 7935104;                 // 16384
static const size_t OFF_T7A  = 7951488;                 // 4096
static const size_t OFF_T7B  = 7955584;                 // 8192
static const size_t OFF_FMA  = 7963776;                 // 9830400  (pd matrix reuses fmA+fmV during KNN)
static const size_t OFF_FMV  = 17794176;                // 9830400
static const size_t OFF_FMB  = 27624576;                // 9830400

// ---------------- small weight transposes ----------------
__global__ void k_transpose(const float* __restrict__ w1, const float* __restrict__ w2,
                            const float* __restrict__ w3, const float* __restrict__ w7a,
                            const float* __restrict__ w7b,
                            float* __restrict__ t1, float* __restrict__ t2,
                            float* __restrict__ t3, float* __restrict__ t7a,
                            float* __restrict__ t7b) {
    int t = blockIdx.x * 256 + threadIdx.x;
    if (t < 4096) {                         // conv1 (64,64) -> [i*64+o]
        int i = t >> 6, o = t & 63; t1[i*64+o] = w1[o*64+i];
    } else if (t < 12288) {                 // conv2 (64,128) -> [i*64+o], i<128
        int r = t - 4096; int i = r >> 6, o = r & 63; t2[i*64+o] = w2[o*128+i];
    } else if (t < 28672) {                 // conv3 (128,128) -> [i*128+o]
        int r = t - 12288; int i = r >> 7, o = r & 127; t3[i*128+o] = w3[o*128+i];
    } else if (t < 32768) {                 // conv7a (64,64) -> [c*64+o]
        int r = t - 28672; int c = r >> 6, o = r & 63; t7a[c*64+o] = w7a[o*64+c];
    } else if (t < 40960) {                 // conv7b (128,64) -> [c*128+po]
        int r = t - 32768; int o = r >> 7, p = r & 127; t7b[o*128+p] = w7b[p*64+o];
    }
}

// ---------------- input row/col sums ----------------
__global__ void k_colsum(const float* __restrict__ img, float* __restrict__ cs) {
    int bc = blockIdx.x; int x = threadIdx.x;   // grid 6, block 640
    const float* p = img + (size_t)bc * H0 * W0;
    float acc = 0.f;
    for (int h = 0; h < H0; ++h) acc += p[h * W0 + x];
    cs[bc * W0 + x] = acc;
}
__global__ void k_rowsum(const float* __restrict__ img, float* __restrict__ rs) {
    int bc = blockIdx.x; int y = threadIdx.x;   // grid 6, block 480
    const float* p = img + (size_t)bc * H0 * W0 + (size_t)y * W0;
    float acc = 0.f;
    for (int x = 0; x < W0; ++x) acc += p[x];
    rs[bc * H0 + y] = acc;
}

// ---------------- pooled conv means ph/pw ----------------
__global__ void k_ph(const float* __restrict__ img, const float* __restrict__ rs,
                     const float* __restrict__ w, const float* __restrict__ bias,
                     float* __restrict__ ph) {
    int t = blockIdx.x * 256 + threadIdx.x;
    if (t >= B_ * 24 * H0) return;
    int h = t % H0; int bc = t / H0; int c = bc % 24; int b = bc / 24;
    float acc = 0.f;
    for (int ic = 0; ic < 3; ++ic)
        for (int dy = 0; dy < 3; ++dy) {
            int y = h + dy - 1;
            if ((unsigned)y >= (unsigned)H0) continue;
            float r = rs[(b*3+ic)*H0 + y];
            const float* row = img + (size_t)((b*3+ic)*H0 + y) * W0;
            float e0 = row[0], eL = row[W0-1];
            const float* wp = w + ((c*3+ic)*3+dy)*3;
            acc += wp[0]*(r - eL) + wp[1]*r + wp[2]*(r - e0);
        }
    ph[t] = bias[c] + acc / 640.0f;
}
__global__ void k_pw(const float* __restrict__ img, const float* __restrict__ cs,
                     const float* __restrict__ w, const float* __restrict__ bias,
                     float* __restrict__ pw) {
    int t = blockIdx.x * 256 + threadIdx.x;
    if (t >= B_ * 24 * W0) return;
    int x = t % W0; int bc = t / W0; int c = bc % 24; int b = bc / 24;
    float acc = 0.f;
    for (int ic = 0; ic < 3; ++ic)
        for (int dx = 0; dx < 3; ++dx) {
            int xx = x + dx - 1;
            if ((unsigned)xx >= (unsigned)W0) continue;
            float csv = cs[(b*3+ic)*W0 + xx];
            const float* base = img + (size_t)(b*3+ic) * H0 * W0;
            float top = base[xx];                   // h=0
            float bot = base[(size_t)(H0-1)*W0 + xx];
            const float* wp = w + ((c*3+ic)*3)*3 + dx;
            acc += wp[0]*(csv - bot) + wp[3]*csv + wp[6]*(csv - top);
        }
    pw[t] = bias[c] + acc / 480.0f;
}

// ---------------- coord-attention mid + gates ----------------
__global__ void k_y8(const float* __restrict__ ph, const float* __restrict__ pw,
                     const float* __restrict__ c1w, const float* __restrict__ c1b,
                     const float* __restrict__ bnp, float* __restrict__ y8) {
    int t = blockIdx.x * 256 + threadIdx.x;
    if (t >= B_ * 8 * 1120) return;
    int pos = t % 1120; int bj = t / 1120; int j = bj % 8; int b = bj / 8;
    float s = c1b[j];
    for (int c = 0; c < 24; ++c) {
        float yv = (pos < H0) ? ph[(b*24+c)*H0 + pos] : pw[(b*24+c)*W0 + (pos - H0)];
        s = fmaf(c1w[j*24+c], yv, s);
    }
    float g = bnp[j], be = bnp[8+j], m = bnp[16+j], va = bnp[24+j];
    float v = (s - m) * (g / sqrtf(va + 1e-5f)) + be;
    float hs = v * fminf(fmaxf(v + 3.f, 0.f), 6.f) * (1.f/6.f);
    y8[(b*8+j)*1120 + pos] = hs;
}
__global__ void k_ahw(const float* __restrict__ y8,
                      const float* __restrict__ chw, const float* __restrict__ chb,
                      const float* __restrict__ cww, const float* __restrict__ cwb,
                      float* __restrict__ ah, float* __restrict__ aw) {
    int t = blockIdx.x * 256 + threadIdx.x;
    if (t >= B_ * 24 * 1120) return;
    int pos = t % 1120; int bc = t / 1120; int c = bc % 24; int b = bc / 24;
    if (pos < H0) {
        float s = chb[c];
        for (int j = 0; j < 8; ++j) s = fmaf(chw[c*8+j], y8[(b*8+j)*1120 + pos], s);
        ah[(b*24+c)*H0 + pos] = 1.f / (1.f + expf(-s));
    } else {
        float s = cwb[c];
        for (int j = 0; j < 8; ++j) s = fmaf(cww[c*8+j], y8[(b*8+j)*1120 + pos], s);
        aw[(b*24+c)*W0 + (pos - H0)] = 1.f / (1.f + expf(-s));
    }
}

// ---------------- feat3d gather (+v/u + idx output) ----------------
__global__ void k_feat3d(const float* __restrict__ pc, const float* __restrict__ img,
                         const float* __restrict__ w, const float* __restrict__ bias,
                         const float* __restrict__ ah, const float* __restrict__ aw,
                         float* __restrict__ f3d, int* __restrict__ vbuf,
                         int* __restrict__ ubuf, float* __restrict__ idx_out) {
    int t = blockIdx.x * 256 + threadIdx.x;
    if (t >= BN_ * 32) return;
    int c = t & 31; int bn = t >> 5; int b = bn >> 12; int n = bn & (N_-1);
    float pv = pc[(b*8 + 0)*N_ + n];
    float pu = pc[(b*8 + 1)*N_ + n];
    int v = (int)floorf(pv + 240.f);
    int u = (int)floorf(pu + 320.f);
    float f;
    if (c < 8) {
        f = pc[(b*8 + c)*N_ + n];
    } else {
        int co = c - 8;
        float acc = bias[co];
        for (int ic = 0; ic < 3; ++ic)
            for (int dy = 0; dy < 3; ++dy) {
                int y = v + dy - 1;
                if ((unsigned)y >= (unsigned)H0) continue;
                for (int dx = 0; dx < 3; ++dx) {
                    int x = u + dx - 1;
                    if ((unsigned)x >= (unsigned)W0) continue;
                    acc = fmaf(w[((co*3+ic)*3+dy)*3+dx],
                               img[((size_t)(b*3+ic)*H0 + y)*W0 + x], acc);
                }
            }
        f = acc * ah[(b*24+co)*H0 + v] * aw[(b*24+co)*W0 + u];
    }
    f3d[(size_t)bn*32 + c] = f;
    if (c == 0) {
        vbuf[bn] = v; ubuf[bn] = u;
        idx_out[bn] = (float)b;
        idx_out[BN_ + bn] = (float)(v >> 1);
        idx_out[2*BN_ + bn] = (float)(u >> 1);
    }
}

// ---------------- squared norms ----------------
template<int C>
__global__ void k_sqnorm(const float* __restrict__ X, float* __restrict__ XX) {
    int t = blockIdx.x * 256 + threadIdx.x;
    if (t >= BN_) return;
    float acc = 0.f;
    const float* p = X + (size_t)t * C;
#pragma unroll
    for (int i = 0; i < C; ++i) acc = fmaf(p[i], p[i], acc);
    XX[t] = acc;
}

// ---------------- distance matrix: pd[q][c] = 2<xq,xc> - |xq|^2 - |xc|^2 ----
// 64x64 tile per block, 4x4 per thread, one batch per launch.
template<int C>
__launch_bounds__(256)
__global__ void k_dist(const float* __restrict__ X, const float* __restrict__ XX,
                       float* __restrict__ pd, int b) {
    __shared__ float As[C][64];   // queries  (rows of output tile)
    __shared__ float Bs[C][64];   // columns
    int bi = blockIdx.x;
    int I = bi >> 6, J = bi & 63;
    int tid = threadIdx.x;
    {   // stage
        int r = tid >> 2;
        int kc0 = (tid & 3) * (C / 4);
        const float* qa = X + ((size_t)(b * N_ + I * 64 + r)) * C + kc0;
        const float* ca = X + ((size_t)(b * N_ + J * 64 + r)) * C + kc0;
#pragma unroll
        for (int i4 = 0; i4 < C / 16; ++i4) {
            float4 va = *(const float4*)(qa + i4 * 4);
            float4 vb = *(const float4*)(ca + i4 * 4);
            int k = kc0 + i4 * 4;
            As[k+0][r] = va.x; As[k+1][r] = va.y; As[k+2][r] = va.z; As[k+3][r] = va.w;
            Bs[k+0][r] = vb.x; Bs[k+1][r] = vb.y; Bs[k+2][r] = vb.z; Bs[k+3][r] = vb.w;
        }
    }
    __syncthreads();
    int tx = tid & 15, ty = tid >> 4;
    float acc[4][4] = {{0.f}};
#pragma unroll
    for (int k = 0; k < C; ++k) {
        float4 a4 = *(const float4*)&As[k][ty * 4];
        float4 b4 = *(const float4*)&Bs[k][tx * 4];
        float av[4] = {a4.x, a4.y, a4.z, a4.w};
        float bv[4] = {b4.x, b4.y, b4.z, b4.w};
#pragma unroll
        for (int i = 0; i < 4; ++i)
#pragma unroll
            for (int j = 0; j < 4; ++j)
                acc[i][j] = fmaf(av[i], bv[j], acc[i][j]);
    }
    float xq[4], xc[4];
#pragma unroll
    for (int i = 0; i < 4; ++i) {
        xq[i] = XX[b * N_ + I * 64 + ty * 4 + i];
        xc[i] = XX[b * N_ + J * 64 + tx * 4 + i];
    }
#pragma unroll
    for (int i = 0; i < 4; ++i) {
        float4 o;
        o.x = 2.f * acc[i][0] - xq[i] - xc[0];
        o.y = 2.f * acc[i][1] - xq[i] - xc[1];
        o.z = 2.f * acc[i][2] - xq[i] - xc[2];
        o.w = 2.f * acc[i][3] - xq[i] - xc[3];
        *(float4*)&pd[(size_t)(I * 64 + ty * 4 + i) * N_ + J * 64 + tx * 4] = o;
    }
}

// ---------------- wave-per-query top-20 ----------------
// Each lane scans 64 candidates (coalesced float4), keeps sorted top-12.
// Then 20 rounds of shuffle-butterfly pop-max with (val, lower-idx) tie-break.
__launch_bounds__(256)
__global__ void k_select(const float* __restrict__ pd, int* __restrict__ idxb, int b) {
    int wv = threadIdx.x >> 6, lane = threadIdx.x & 63;
    int q = blockIdx.x * 4 + wv;
    const float* row = pd + (size_t)q * N_;
    float val[12]; int idx[12];
#pragma unroll
    for (int j = 0; j < 12; ++j) { val[j] = -INFINITY; idx[j] = 0x7fffffff; }
    for (int t = 0; t < N_ / 256; ++t) {
        float4 v4 = *(const float4*)(row + t * 256 + lane * 4);
        float vv[4] = {v4.x, v4.y, v4.z, v4.w};
#pragma unroll
        for (int j = 0; j < 4; ++j) {
            float v = vv[j];
            if (v > val[11]) {
                float cv = v; int cc = t * 256 + lane * 4 + j; bool ins = false;
#pragma unroll
                for (int s = 0; s < 12; ++s) {
                    bool sw = ins || (cv > val[s]);
                    if (sw) {
                        float tv = val[s]; val[s] = cv; cv = tv;
                        int ti = idx[s]; idx[s] = cc; cc = ti;
                        ins = true;
                    }
                }
            }
        }
    }
    int nb = 0;
    float hv = val[0]; int hi = idx[0];
#pragma unroll 1
    for (int slot = 0; slot < KNN_K; ++slot) {
        float wvv = hv; int wi = hi; int wl = lane;
#pragma unroll
        for (int off = 1; off < 64; off <<= 1) {
            float ov = __shfl_xor(wvv, off);
            int   oi = __shfl_xor(wi, off);
            int   ol = __shfl_xor(wl, off);
            bool take = (ov > wvv) || (ov == wvv && oi < wi);
            if (take) { wvv = ov; wi = oi; wl = ol; }
        }
        if (lane == slot) nb = wi;
        bool pop = (lane == wl);
#pragma unroll
        for (int s = 0; s < 11; ++s)
            if (pop) { val[s] = val[s+1]; idx[s] = idx[s+1]; }
        if (pop) { val[11] = -INFINITY; idx[11] = 0x7fffffff; }
        hv = val[0]; hi = idx[0];
    }
    if (lane < KNN_K) idxb[(size_t)(b * N_ + q) * KNN_K + lane] = nb;
}

// ---------------- EdgeConv: gather + 1x1 conv + bn + lrelu + max_k ----------------
template<int CIN, int COUT, int P>   // P*COUT == 256
__launch_bounds__(256)
__global__ void edgeconv(const float* __restrict__ X, const int* __restrict__ idxb,
                         const float* __restrict__ wT, const float* __restrict__ bnp,
                         float* __restrict__ Y) {
    __shared__ float sctr[P][CIN];
    __shared__ float snb[P][KNN_K * CIN];
    int base = blockIdx.x * P;
    int tid = threadIdx.x;
    for (int j = tid; j < P * CIN; j += 256) {
        int p = j / CIN, i = j % CIN;
        sctr[p][i] = X[(size_t)(base + p) * CIN + i];
    }
    for (int j = tid; j < P * KNN_K * CIN; j += 256) {
        int p = j / (KNN_K * CIN); int r = j % (KNN_K * CIN);
        int k = r / CIN; int i = r % CIN;
        int b = (base + p) / N_;
        int ni = idxb[(size_t)(base + p) * KNN_K + k];
        snb[p][k * CIN + i] = X[((size_t)b * N_ + ni) * CIN + i];
    }
    __syncthreads();
    int p = tid / COUT, o = tid % COUT;
    float g = bnp[o], bb = bnp[COUT + o], m = bnp[2*COUT + o], va = bnp[3*COUT + o];
    float a = g / sqrtf(va + 1e-5f);
    float sh = bb - m * a;
    float accc = 0.f;
#pragma unroll
    for (int i = 0; i < CIN; ++i)
        accc = fmaf(wT[(CIN + i) * COUT + o] - wT[i * COUT + o], sctr[p][i], accc);
    float mx = -INFINITY;
    for (int k = 0; k < KNN_K; ++k) {
        float s = accc;
#pragma unroll
        for (int i = 0; i < CIN; ++i)
            s = fmaf(wT[i * COUT + o], snb[p][k * CIN + i], s);
        float r = fmaf(s, a, sh);
        r = (r >= 0.f) ? r : 0.2f * r;
        mx = fmaxf(mx, r);
    }
    Y[(size_t)(base + p) * COUT + o] = mx;
}

// ---------------- lin4 (256->256->64), 4 points/block, + scatter-add --------
__launch_bounds__(256)
__global__ void k_lin4(const float* __restrict__ x1, const float* __restrict__ x2,
                       const float* __restrict__ x3, const float* __restrict__ l4a,
                       const float* __restrict__ l4b, const int* __restrict__ vbuf,
                       const int* __restrict__ ubuf, float* __restrict__ fmA) {
    int p0 = blockIdx.x * 4; int tid = threadIdx.x;
    __shared__ float xc[4][256]; __shared__ float t1s[4][256];
    for (int j = tid; j < 1024; j += 256) {
        int p = j >> 8, i = j & 255;
        int bn = p0 + p;
        float v;
        if (i < 64)       v = x1[(size_t)bn*64 + i];
        else if (i < 128) v = x2[(size_t)bn*64 + i - 64];
        else              v = x3[(size_t)bn*128 + i - 128];
        xc[p][i] = v;
    }
    __syncthreads();
    float acc[4] = {0.f, 0.f, 0.f, 0.f};
#pragma unroll 8
    for (int i = 0; i < 256; ++i) {
        float wv = l4a[i*256 + tid];
#pragma unroll
        for (int p = 0; p < 4; ++p) acc[p] = fmaf(xc[p][i], wv, acc[p]);
    }
#pragma unroll
    for (int p = 0; p < 4; ++p) t1s[p][tid] = acc[p];
    __syncthreads();
    int o = tid & 63, pg = tid >> 6;
    float a2 = 0.f;
#pragma unroll 8
    for (int i = 0; i < 256; ++i) a2 = fmaf(t1s[pg][i], l4b[i*64 + o], a2);
    int bn = p0 + pg;
    int b = bn >> 12; int v = vbuf[bn] >> 1; int u = ubuf[bn] >> 1;
    atomicAdd(fmA + ((size_t)(b*FH_ + v)*FW_ + u)*64 + o, a2);
}

// ---------------- per-pixel channel softmax ----------------
__global__ void k_softmax(float* __restrict__ fm) {
    int pix = blockIdx.x * 4 + (threadIdx.x >> 6);
    int l = threadIdx.x & 63;
    float x = fm[(size_t)pix*64 + l];
    float m = x;
    for (int off = 32; off > 0; off >>= 1) m = fmaxf(m, __shfl_xor(m, off));
    float e = expf(x - m);
    float s = e;
    for (int off = 32; off > 0; off >>= 1) s += __shfl_xor(s, off);
    fm[(size_t)pix*64 + l] = e / s;
}

// ---------------- DCN value GEMV ----------------
__global__ void k_dcnval(const float* __restrict__ in, const float* __restrict__ vw,
                         const float* __restrict__ vb, float* __restrict__ val) {
    __shared__ float sx[256];
    int tid = threadIdx.x;
    size_t base = (size_t)blockIdx.x * 256;
    sx[tid] = in[base + tid];
    __syncthreads();
    int o = tid & 63; int grp = tid >> 6;
    const float* xr = sx + grp*64;
    float a0 = vb[o], a1 = 0.f;
#pragma unroll 8
    for (int i = 0; i < 64; i += 2) {
        a0 = fmaf(xr[i],   vw[i*64 + o],     a0);
        a1 = fmaf(xr[i+1], vw[(i+1)*64 + o], a1);
    }
    val[base + tid] = a0 + a1;
}

// ---------------- DCN: wave-per-pixel, branch-free batched sampling --------
__launch_bounds__(256)
__global__ void k_dcnsamp(const float* __restrict__ in, const float* __restrict__ val,
                          const float* __restrict__ ow, const float* __restrict__ ob,
                          const float* __restrict__ pwm, const float* __restrict__ pbm,
                          const float* __restrict__ bnp, float* __restrict__ out) {
    int wv = threadIdx.x >> 6, lane = threadIdx.x & 63;
    int pix = blockIdx.x * 4 + wv;
    int b = pix / (FH_*FW_); int hw = pix % (FH_*FW_);
    int h = hw / FW_; int w = hw % FW_;
    __shared__ float sx[4][64];
    __shared__ float som[4][112];
    __shared__ float stap[4][36][8];
    __shared__ float ss[4][64];

    sx[wv][lane] = in[(size_t)pix*64 + lane];
    __syncthreads();

    // offset head: 108 outputs, lanes produce o=lane and o=lane+64 (lane<44)
    {
        float a0 = ob[lane];
        float a1 = (lane < 44) ? ob[64 + lane] : 0.f;
#pragma unroll 8
        for (int i = 0; i < 64; ++i) {
            float xv = sx[wv][i];
            a0 = fmaf(xv, ow[i*108 + lane], a0);
            if (lane < 44) a1 = fmaf(xv, ow[i*108 + 64 + lane], a1);
        }
        som[wv][lane] = a0;
        if (lane < 44) som[wv][64 + lane] = a1;
    }
    __syncthreads();

    // tap precompute: lanes 0..35 -> (g,k): clamped addresses + masked weights
    if (lane < 36) {
        int g = lane / 9, k = lane % 9;
        float lx = (float)(w + (k % 3) - 1) + som[wv][g*27 + k*3 + 0];
        float ly = (float)(h + (k / 3) - 1) + som[wv][g*27 + k*3 + 1];
        float msk = som[wv][g*27 + k*3 + 2];
        float x0f = floorf(lx), y0f = floorf(ly);
        float wx = lx - x0f, wy = ly - y0f;
        int x0 = (int)x0f, y0 = (int)y0f;
        bool xi0 = (unsigned)x0 < (unsigned)FW_, xi1 = (unsigned)(x0+1) < (unsigned)FW_;
        bool yi0 = (unsigned)y0 < (unsigned)FH_, yi1 = (unsigned)(y0+1) < (unsigned)FH_;
        int x0c = min(max(x0, 0), FW_-1), x1c = min(max(x0+1, 0), FW_-1);
        int y0c = min(max(y0, 0), FH_-1), y1c = min(max(y0+1, 0), FH_-1);
        stap[wv][lane][0] = __int_as_float((y0c*FW_ + x0c) * 64);
        stap[wv][lane][1] = __int_as_float((y0c*FW_ + x1c) * 64);
        stap[wv][lane][2] = __int_as_float((y1c*FW_ + x0c) * 64);
        stap[wv][lane][3] = __int_as_float((y1c*FW_ + x1c) * 64);
        stap[wv][lane][4] = (xi0 && yi0) ? msk*(1.f-wx)*(1.f-wy) : 0.f;
        stap[wv][lane][5] = (xi1 && yi0) ? msk*wx*(1.f-wy)       : 0.f;
        stap[wv][lane][6] = (xi0 && yi1) ? msk*(1.f-wx)*wy       : 0.f;
        stap[wv][lane][7] = (xi1 && yi1) ? msk*wx*wy             : 0.f;
    }
    __syncthreads();

    // sampling: lane = channel; 36 independent unconditional loads
    {
        const float* vbp = val + (size_t)b * (FH_*FW_) * 64 + lane;
        int g9 = (lane >> 4) * 9;
        float acc0 = 0.f, acc1 = 0.f;
#pragma unroll
        for (int k = 0; k < 9; ++k) {
            int tp = g9 + k;
            int a00 = __float_as_int(stap[wv][tp][0]);
            int a01 = __float_as_int(stap[wv][tp][1]);
            int a10 = __float_as_int(stap[wv][tp][2]);
            int a11 = __float_as_int(stap[wv][tp][3]);
            float v00 = vbp[a00], v01 = vbp[a01], v10 = vbp[a10], v11 = vbp[a11];
            acc0 = fmaf(stap[wv][tp][4], v00, acc0);
            acc1 = fmaf(stap[wv][tp][5], v01, acc1);
            acc0 = fmaf(stap[wv][tp][6], v10, acc0);
            acc1 = fmaf(stap[wv][tp][7], v11, acc1);
        }
        ss[wv][lane] = acc0 + acc1;
    }
    __syncthreads();

    // out-projection + bn + lrelu
    {
        float a0 = pbm[lane], a1 = 0.f;
#pragma unroll 8
        for (int i = 0; i < 64; i += 2) {
            a0 = fmaf(ss[wv][i],   pwm[i*64 + lane],     a0);
            a1 = fmaf(ss[wv][i+1], pwm[(i+1)*64 + lane], a1);
        }
        float a = a0 + a1;
        float g = bnp[lane], be = bnp[64+lane], m = bnp[128+lane], va = bnp[192+lane];
        float sc = g / sqrtf(va + 1e-5f);
        float r = (a - m) * sc + be;
        out[(size_t)pix*64 + lane] = (r >= 0.f) ? r : 0.2f * r;
    }
}

// ---------------- conv7a + conv7b, 16 pixels/block, coalesced stores -------
__launch_bounds__(256)
__global__ void k_conv7(const float* __restrict__ in, const float* __restrict__ w7aT,
                        const float* __restrict__ w7bT, float* __restrict__ out) {
    int blk = blockIdx.x;                    // PIX_/16 blocks
    int b = blk / ((FH_*FW_)/16);
    int hw0 = (blk % ((FH_*FW_)/16)) * 16;
    int tid = threadIdx.x;
    __shared__ float sx[16][64];
    __shared__ float st[16][64];
    for (int j = tid; j < 1024; j += 256) {
        int p = j >> 6, c = j & 63;
        sx[p][c] = in[((size_t)(b*(FH_*FW_) + hw0 + p))*64 + c];
    }
    __syncthreads();
    {
        int o = tid & 63, p4 = tid >> 6;
        float acc[4] = {0.f, 0.f, 0.f, 0.f};
#pragma unroll 8
        for (int c = 0; c < 64; ++c) {
            float wv = w7aT[c*64 + o];
#pragma unroll
            for (int j = 0; j < 4; ++j) acc[j] = fmaf(sx[p4*4+j][c], wv, acc[j]);
        }
#pragma unroll
        for (int j = 0; j < 4; ++j) st[p4*4+j][o] = acc[j];
    }
    __syncthreads();
    {
        int po = tid >> 1, half = tid & 1;
        float acc[8] = {0.f};
#pragma unroll 8
        for (int c = 0; c < 64; ++c) {
            float wv = w7bT[c*128 + po];
#pragma unroll
            for (int j = 0; j < 8; ++j) acc[j] = fmaf(st[half*8+j][c], wv, acc[j]);
        }
        float* op = out + ((size_t)b*128 + po)*(FH_*FW_) + hw0 + half*8;
        *(float4*)op       = make_float4(acc[0], acc[1], acc[2], acc[3]);
        *(float4*)(op + 4) = make_float4(acc[4], acc[5], acc[6], acc[7]);
    }
}

// ---------------- launch ----------------
extern "C" void kernel_launch(void* const* d_in, const int* in_sizes, int n_in,
                              void* d_out, int out_size, void* d_ws, size_t ws_size,
                              hipStream_t stream) {
    (void)in_sizes; (void)n_in; (void)out_size; (void)ws_size;
    const float* pc   = (const float*)d_in[0];
    const float* img  = (const float*)d_in[1];
    const float* pcw  = (const float*)d_in[2];
    const float* pcb  = (const float*)d_in[3];
    const float* c1w  = (const float*)d_in[4];
    const float* c1b  = (const float*)d_in[5];
    const float* cabn = (const float*)d_in[6];
    const float* chw  = (const float*)d_in[7];
    const float* chb  = (const float*)d_in[8];
    const float* cww  = (const float*)d_in[9];
    const float* cwb  = (const float*)d_in[10];
    const float* w1   = (const float*)d_in[11];
    const float* bn1  = (const float*)d_in[12];
    const float* w2   = (const float*)d_in[13];
    const float* bn2  = (const float*)d_in[14];
    const float* w3   = (const float*)d_in[15];
    const float* bn3  = (const float*)d_in[16];
    const float* l4a  = (const float*)d_in[17];
    const float* l4b  = (const float*)d_in[18];
    const float* d5ow = (const float*)d_in[19];
    const float* d5ob = (const float*)d_in[20];
    const float* d5vw = (const float*)d_in[21];
    const float* d5vb = (const float*)d_in[22];
    const float* d5pw = (const float*)d_in[23];
    const float* d5pb = (const float*)d_in[24];
    const float* bn5  = (const float*)d_in[25];
    const float* d6ow = (const float*)d_in[26];
    const float* d6ob = (const float*)d_in[27];
    const float* d6vw = (const float*)d_in[28];
    const float* d6vb = (const float*)d_in[29];
    const float* d6pw = (const float*)d_in[30];
    const float* d6pb = (const float*)d_in[31];
    const float* bn6  = (const float*)d_in[32];
    const float* w7a  = (const float*)d_in[33];
    const float* w7b  = (const float*)d_in[34];

    float* ws  = (float*)d_ws;
    float* out = (float*)d_out;

    float* rs  = ws + OFF_RS;   float* cs  = ws + OFF_CS;
    float* ph  = ws + OFF_PH;   float* pw  = ws + OFF_PW;
    float* y8  = ws + OFF_Y8;   float* ah  = ws + OFF_AH;  float* aw = ws + OFF_AW;
    int*   vb  = (int*)(ws + OFF_VB);
    int*   ub  = (int*)(ws + OFF_UB);
    float* f3d = ws + OFF_F3D;  float* xx  = ws + OFF_XX;
    int*   idxb = (int*)(ws + OFF_IDX);
    float* x1  = ws + OFF_X1;   float* x2  = ws + OFF_X2;  float* x3 = ws + OFF_X3;
    float* t1  = ws + OFF_T1;   float* t2  = ws + OFF_T2;  float* t3 = ws + OFF_T3;
    float* t7a = ws + OFF_T7A;  float* t7b = ws + OFF_T7B;
    float* fmA = ws + OFF_FMA;  float* fmV = ws + OFF_FMV; float* fmB = ws + OFF_FMB;
    float* pdb = ws + OFF_FMA;  // pd matrix (67 MB) reuses fmA+fmV region during KNN

    k_transpose<<<160, 256, 0, stream>>>(w1, w2, w3, w7a, w7b, t1, t2, t3, t7a, t7b);
    k_colsum<<<B_*3, W0, 0, stream>>>(img, cs);
    k_rowsum<<<B_*3, H0, 0, stream>>>(img, rs);
    k_ph<<<(B_*24*H0 + 255)/256, 256, 0, stream>>>(img, rs, pcw, pcb, ph);
    k_pw<<<(B_*24*W0 + 255)/256, 256, 0, stream>>>(img, cs, pcw, pcb, pw);
    k_y8<<<(B_*8*1120 + 255)/256, 256, 0, stream>>>(ph, pw, c1w, c1b, cabn, y8);
    k_ahw<<<(B_*24*1120 + 255)/256, 256, 0, stream>>>(y8, chw, chb, cww, cwb, ah, aw);
    k_feat3d<<<(BN_*32)/256, 256, 0, stream>>>(pc, img, pcw, pcb, ah, aw, f3d, vb, ub,
                                               out + (size_t)B_*128*FH_*FW_);

    // EdgeConv stage 1 (C=32)
    k_sqnorm<32><<<BN_/256, 256, 0, stream>>>(f3d, xx);
    for (int b = 0; b < B_; ++b) {
        k_dist<32><<<4096, 256, 0, stream>>>(f3d, xx, pdb, b);
        k_select<<<N_/4, 256, 0, stream>>>(pdb, idxb, b);
    }
    edgeconv<32,64,4><<<BN_/4, 256, 0, stream>>>(f3d, idxb, t1, bn1, x1);
    // stage 2 (C=64)
    k_sqnorm<64><<<BN_/256, 256, 0, stream>>>(x1, xx);
    for (int b = 0; b < B_; ++b) {
        k_dist<64><<<4096, 256, 0, stream>>>(x1, xx, pdb, b);
        k_select<<<N_/4, 256, 0, stream>>>(pdb, idxb, b);
    }
    edgeconv<64,64,4><<<BN_/4, 256, 0, stream>>>(x1, idxb, t2, bn2, x2);
    // stage 3 (C=64)
    k_sqnorm<64><<<BN_/256, 256, 0, stream>>>(x2, xx);
    for (int b = 0; b < B_; ++b) {
        k_dist<64><<<4096, 256, 0, stream>>>(x2, xx, pdb, b);
        k_select<<<N_/4, 256, 0, stream>>>(pdb, idxb, b);
    }
    edgeconv<64,128,2><<<BN_/2, 256, 0, stream>>>(x2, idxb, t3, bn3, x3);

    // fm pipeline (fmA/fmV free again from here)
    hipMemsetAsync(fmA, 0, (size_t)PIX_ * 64 * sizeof(float), stream);
    k_lin4<<<BN_/4, 256, 0, stream>>>(x1, x2, x3, l4a, l4b, vb, ub, fmA);
    k_softmax<<<PIX_/4, 256, 0, stream>>>(fmA);

    k_dcnval<<<PIX_*64/256, 256, 0, stream>>>(fmA, d5vw, d5vb, fmV);
    k_dcnsamp<<<PIX_/4, 256, 0, stream>>>(fmA, fmV, d5ow, d5ob, d5pw, d5pb, bn5, fmB);
    k_dcnval<<<PIX_*64/256, 256, 0, stream>>>(fmB, d6vw, d6vb, fmV);
    k_dcnsamp<<<PIX_/4, 256, 0, stream>>>(fmB, fmV, d6ow, d6ob, d6pw, d6pb, bn6, fmA);

    k_conv7<<<PIX_/16, 256, 0, stream>>>(fmA, t7a, t7b, out);
}

// Round 4
// 1918.585 us; speedup vs baseline: 2.7067x; 1.2546x over previous
//
#include <hip/hip_runtime.h>
#include <math.h>

#define B_    2
#define N_    4096
#define BN_   (B_*N_)
#define H0    480
#define W0    640
#define FH_   240
#define FW_   320
#define PIX_  (B_*FH_*FW_)     // 153600
#define KNN_K 20

// ---------------- workspace layout (float offsets) ----------------
static const size_t OFF_RS   = 0;
static const size_t OFF_CS   = 2944;
static const size_t OFF_PH   = 6784;
static const size_t OFF_PW   = 29824;
static const size_t OFF_Y8   = 60544;
static const size_t OFF_AH   = 78464;
static const size_t OFF_AW   = 101504;
static const size_t OFF_VB   = 132224;
static const size_t OFF_UB   = 140416;
static const size_t OFF_F3D  = 148608;
static const size_t OFF_XX   = 410752;
static const size_t OFF_IDX  = 5661824;
static const size_t OFF_X1   = 5825664;
static const size_t OFF_X2   = 6349952;
static const size_t OFF_X3   = 6874240;
static const size_t OFF_T1   = 7922816;
static const size_t OFF_T2   = 7926912;
static const size_t OFF_T3   = 7935104;
static const size_t OFF_T7A  = 7951488;
static const size_t OFF_T7B  = 7955584;
static const size_t OFF_FMA  = 7963776;   // pd matrix reuses fmA+fmV during KNN
static const size_t OFF_FMV  = 17794176;
static const size_t OFF_FMB  = 27624576;

// ---------------- small weight transposes ----------------
__global__ void k_transpose(const float* __restrict__ w1, const float* __restrict__ w2,
                            const float* __restrict__ w3, const float* __restrict__ w7a,
                            const float* __restrict__ w7b,
                            float* __restrict__ t1, float* __restrict__ t2,
                            float* __restrict__ t3, float* __restrict__ t7a,
                            float* __restrict__ t7b) {
    int t = blockIdx.x * 256 + threadIdx.x;
    if (t < 4096) {
        int i = t >> 6, o = t & 63; t1[i*64+o] = w1[o*64+i];
    } else if (t < 12288) {
        int r = t - 4096; int i = r >> 6, o = r & 63; t2[i*64+o] = w2[o*128+i];
    } else if (t < 28672) {
        int r = t - 12288; int i = r >> 7, o = r & 127; t3[i*128+o] = w3[o*128+i];
    } else if (t < 32768) {
        int r = t - 28672; int c = r >> 6, o = r & 63; t7a[c*64+o] = w7a[o*64+c];
    } else if (t < 40960) {
        int r = t - 32768; int o = r >> 7, p = r & 127; t7b[o*128+p] = w7b[p*64+o];
    }
}

// ---------------- input row/col sums ----------------
__global__ void k_colsum(const float* __restrict__ img, float* __restrict__ cs) {
    int bc = blockIdx.x; int x = threadIdx.x;
    const float* p = img + (size_t)bc * H0 * W0;
    float acc = 0.f;
    for (int h = 0; h < H0; ++h) acc += p[h * W0 + x];
    cs[bc * W0 + x] = acc;
}
__global__ void k_rowsum(const float* __restrict__ img, float* __restrict__ rs) {
    int bc = blockIdx.x; int y = threadIdx.x;
    const float* p = img + (size_t)bc * H0 * W0 + (size_t)y * W0;
    float acc = 0.f;
    for (int x = 0; x < W0; ++x) acc += p[x];
    rs[bc * H0 + y] = acc;
}

// ---------------- pooled conv means ph/pw ----------------
__global__ void k_ph(const float* __restrict__ img, const float* __restrict__ rs,
                     const float* __restrict__ w, const float* __restrict__ bias,
                     float* __restrict__ ph) {
    int t = blockIdx.x * 256 + threadIdx.x;
    if (t >= B_ * 24 * H0) return;
    int h = t % H0; int bc = t / H0; int c = bc % 24; int b = bc / 24;
    float acc = 0.f;
    for (int ic = 0; ic < 3; ++ic)
        for (int dy = 0; dy < 3; ++dy) {
            int y = h + dy - 1;
            if ((unsigned)y >= (unsigned)H0) continue;
            float r = rs[(b*3+ic)*H0 + y];
            const float* row = img + (size_t)((b*3+ic)*H0 + y) * W0;
            float e0 = row[0], eL = row[W0-1];
            const float* wp = w + ((c*3+ic)*3+dy)*3;
            acc += wp[0]*(r - eL) + wp[1]*r + wp[2]*(r - e0);
        }
    ph[t] = bias[c] + acc / 640.0f;
}
__global__ void k_pw(const float* __restrict__ img, const float* __restrict__ cs,
                     const float* __restrict__ w, const float* __restrict__ bias,
                     float* __restrict__ pw) {
    int t = blockIdx.x * 256 + threadIdx.x;
    if (t >= B_ * 24 * W0) return;
    int x = t % W0; int bc = t / W0; int c = bc % 24; int b = bc / 24;
    float acc = 0.f;
    for (int ic = 0; ic < 3; ++ic)
        for (int dx = 0; dx < 3; ++dx) {
            int xx = x + dx - 1;
            if ((unsigned)xx >= (unsigned)W0) continue;
            float csv = cs[(b*3+ic)*W0 + xx];
            const float* base = img + (size_t)(b*3+ic) * H0 * W0;
            float top = base[xx];
            float bot = base[(size_t)(H0-1)*W0 + xx];
            const float* wp = w + ((c*3+ic)*3)*3 + dx;
            acc += wp[0]*(csv - bot) + wp[3]*csv + wp[6]*(csv - top);
        }
    pw[t] = bias[c] + acc / 480.0f;
}

// ---------------- coord-attention mid + gates ----------------
__global__ void k_y8(const float* __restrict__ ph, const float* __restrict__ pw,
                     const float* __restrict__ c1w, const float* __restrict__ c1b,
                     const float* __restrict__ bnp, float* __restrict__ y8) {
    int t = blockIdx.x * 256 + threadIdx.x;
    if (t >= B_ * 8 * 1120) return;
    int pos = t % 1120; int bj = t / 1120; int j = bj % 8; int b = bj / 8;
    float s = c1b[j];
    for (int c = 0; c < 24; ++c) {
        float yv = (pos < H0) ? ph[(b*24+c)*H0 + pos] : pw[(b*24+c)*W0 + (pos - H0)];
        s = fmaf(c1w[j*24+c], yv, s);
    }
    float g = bnp[j], be = bnp[8+j], m = bnp[16+j], va = bnp[24+j];
    float v = (s - m) * (g / sqrtf(va + 1e-5f)) + be;
    float hs = v * fminf(fmaxf(v + 3.f, 0.f), 6.f) * (1.f/6.f);
    y8[(b*8+j)*1120 + pos] = hs;
}
__global__ void k_ahw(const float* __restrict__ y8,
                      const float* __restrict__ chw, const float* __restrict__ chb,
                      const float* __restrict__ cww, const float* __restrict__ cwb,
                      float* __restrict__ ah, float* __restrict__ aw) {
    int t = blockIdx.x * 256 + threadIdx.x;
    if (t >= B_ * 24 * 1120) return;
    int pos = t % 1120; int bc = t / 1120; int c = bc % 24; int b = bc / 24;
    if (pos < H0) {
        float s = chb[c];
        for (int j = 0; j < 8; ++j) s = fmaf(chw[c*8+j], y8[(b*8+j)*1120 + pos], s);
        ah[(b*24+c)*H0 + pos] = 1.f / (1.f + expf(-s));
    } else {
        float s = cwb[c];
        for (int j = 0; j < 8; ++j) s = fmaf(cww[c*8+j], y8[(b*8+j)*1120 + pos], s);
        aw[(b*24+c)*W0 + (pos - H0)] = 1.f / (1.f + expf(-s));
    }
}

// ---------------- feat3d gather (+v/u + idx output) ----------------
__global__ void k_feat3d(const float* __restrict__ pc, const float* __restrict__ img,
                         const float* __restrict__ w, const float* __restrict__ bias,
                         const float* __restrict__ ah, const float* __restrict__ aw,
                         float* __restrict__ f3d, int* __restrict__ vbuf,
                         int* __restrict__ ubuf, float* __restrict__ idx_out) {
    int t = blockIdx.x * 256 + threadIdx.x;
    if (t >= BN_ * 32) return;
    int c = t & 31; int bn = t >> 5; int b = bn >> 12; int n = bn & (N_-1);
    float pv = pc[(b*8 + 0)*N_ + n];
    float pu = pc[(b*8 + 1)*N_ + n];
    int v = (int)floorf(pv + 240.f);
    int u = (int)floorf(pu + 320.f);
    float f;
    if (c < 8) {
        f = pc[(b*8 + c)*N_ + n];
    } else {
        int co = c - 8;
        float acc = bias[co];
        for (int ic = 0; ic < 3; ++ic)
            for (int dy = 0; dy < 3; ++dy) {
                int y = v + dy - 1;
                if ((unsigned)y >= (unsigned)H0) continue;
                for (int dx = 0; dx < 3; ++dx) {
                    int x = u + dx - 1;
                    if ((unsigned)x >= (unsigned)W0) continue;
                    acc = fmaf(w[((co*3+ic)*3+dy)*3+dx],
                               img[((size_t)(b*3+ic)*H0 + y)*W0 + x], acc);
                }
            }
        f = acc * ah[(b*24+co)*H0 + v] * aw[(b*24+co)*W0 + u];
    }
    f3d[(size_t)bn*32 + c] = f;
    if (c == 0) {
        vbuf[bn] = v; ubuf[bn] = u;
        idx_out[bn] = (float)b;
        idx_out[BN_ + bn] = (float)(v >> 1);
        idx_out[2*BN_ + bn] = (float)(u >> 1);
    }
}

// ---------------- squared norms ----------------
template<int C>
__global__ void k_sqnorm(const float* __restrict__ X, float* __restrict__ XX) {
    int t = blockIdx.x * 256 + threadIdx.x;
    if (t >= BN_) return;
    float acc = 0.f;
    const float* p = X + (size_t)t * C;
#pragma unroll
    for (int i = 0; i < C; ++i) acc = fmaf(p[i], p[i], acc);
    XX[t] = acc;
}

// ---------------- distance matrix: 128x128 tile, 8x8 micro-tile ----------
template<int C>
__launch_bounds__(256, 2)
__global__ void k_dist(const float* __restrict__ X, const float* __restrict__ XX,
                       float* __restrict__ pd, int b) {
    __shared__ float As[C*128];
    __shared__ float Bs[C*128];
    int tid = threadIdx.x;
    int I = blockIdx.x >> 5, J = blockIdx.x & 31;
    {
        int r = tid >> 1, c0 = (tid & 1) * (C/2);
        const float* qa = X + ((size_t)(b*N_ + I*128 + r)) * C + c0;
        const float* ca = X + ((size_t)(b*N_ + J*128 + r)) * C + c0;
#pragma unroll
        for (int m = 0; m < C/8; ++m) {
            float4 va = *(const float4*)(qa + m*4);
            float4 vb = *(const float4*)(ca + m*4);
            int c = c0 + m*4;
            As[(c+0)*128+r]=va.x; As[(c+1)*128+r]=va.y; As[(c+2)*128+r]=va.z; As[(c+3)*128+r]=va.w;
            Bs[(c+0)*128+r]=vb.x; Bs[(c+1)*128+r]=vb.y; Bs[(c+2)*128+r]=vb.z; Bs[(c+3)*128+r]=vb.w;
        }
    }
    __syncthreads();
    int tx = tid & 15, ty = tid >> 4;
    float acc[8][8];
#pragma unroll
    for (int i=0;i<8;++i)
#pragma unroll
        for (int j=0;j<8;++j) acc[i][j]=0.f;
    for (int k = 0; k < C; ++k) {
        float4 a0 = *(const float4*)&As[k*128 + ty*8];
        float4 a1 = *(const float4*)&As[k*128 + ty*8 + 4];
        float4 b0 = *(const float4*)&Bs[k*128 + tx*8];
        float4 b1 = *(const float4*)&Bs[k*128 + tx*8 + 4];
        float av[8] = {a0.x,a0.y,a0.z,a0.w,a1.x,a1.y,a1.z,a1.w};
        float bv[8] = {b0.x,b0.y,b0.z,b0.w,b1.x,b1.y,b1.z,b1.w};
#pragma unroll
        for (int i = 0; i < 8; ++i)
#pragma unroll
            for (int j = 0; j < 8; ++j)
                acc[i][j] = fmaf(av[i], bv[j], acc[i][j]);
    }
    float xq[8], xc[8];
#pragma unroll
    for (int i = 0; i < 8; ++i) {
        xq[i] = XX[b*N_ + I*128 + ty*8 + i];
        xc[i] = XX[b*N_ + J*128 + tx*8 + i];
    }
#pragma unroll
    for (int i = 0; i < 8; ++i) {
        int row = I*128 + ty*8 + i;
        float4 o0, o1;
        o0.x = 2.f*acc[i][0] - xq[i] - xc[0]; o0.y = 2.f*acc[i][1] - xq[i] - xc[1];
        o0.z = 2.f*acc[i][2] - xq[i] - xc[2]; o0.w = 2.f*acc[i][3] - xq[i] - xc[3];
        o1.x = 2.f*acc[i][4] - xq[i] - xc[4]; o1.y = 2.f*acc[i][5] - xq[i] - xc[5];
        o1.z = 2.f*acc[i][6] - xq[i] - xc[6]; o1.w = 2.f*acc[i][7] - xq[i] - xc[7];
        *(float4*)&pd[(size_t)row*N_ + J*128 + tx*8]     = o0;
        *(float4*)&pd[(size_t)row*N_ + J*128 + tx*8 + 4] = o1;
    }
}

// ---------------- wave-per-query top-20 ----------------
__launch_bounds__(256)
__global__ void k_select(const float* __restrict__ pd, int* __restrict__ idxb, int b) {
    int wv = threadIdx.x >> 6, lane = threadIdx.x & 63;
    int q = blockIdx.x * 4 + wv;
    const float* row = pd + (size_t)q * N_;
    float val[12]; int idx[12];
#pragma unroll
    for (int j = 0; j < 12; ++j) { val[j] = -INFINITY; idx[j] = 0x7fffffff; }
    for (int t = 0; t < N_ / 256; ++t) {
        float4 v4 = *(const float4*)(row + t * 256 + lane * 4);
        float vv[4] = {v4.x, v4.y, v4.z, v4.w};
#pragma unroll
        for (int j = 0; j < 4; ++j) {
            float v = vv[j];
            if (v > val[11]) {
                float cv = v; int cc = t * 256 + lane * 4 + j; bool ins = false;
#pragma unroll
                for (int s = 0; s < 12; ++s) {
                    bool sw = ins || (cv > val[s]);
                    if (sw) {
                        float tv = val[s]; val[s] = cv; cv = tv;
                        int ti = idx[s]; idx[s] = cc; cc = ti;
                        ins = true;
                    }
                }
            }
        }
    }
    int nb = 0;
    float hv = val[0]; int hi = idx[0];
#pragma unroll 1
    for (int slot = 0; slot < KNN_K; ++slot) {
        float wvv = hv; int wi = hi; int wl = lane;
#pragma unroll
        for (int off = 1; off < 64; off <<= 1) {
            float ov = __shfl_xor(wvv, off);
            int   oi = __shfl_xor(wi, off);
            int   ol = __shfl_xor(wl, off);
            bool take = (ov > wvv) || (ov == wvv && oi < wi);
            if (take) { wvv = ov; wi = oi; wl = ol; }
        }
        if (lane == slot) nb = wi;
        bool pop = (lane == wl);
#pragma unroll
        for (int s = 0; s < 11; ++s)
            if (pop) { val[s] = val[s+1]; idx[s] = idx[s+1]; }
        if (pop) { val[11] = -INFINITY; idx[11] = 0x7fffffff; }
        hv = val[0]; hi = idx[0];
    }
    if (lane < KNN_K) idxb[(size_t)(b * N_ + q) * KNN_K + lane] = nb;
}

// ---------------- EdgeConv: weights hoisted into registers ----------------
template<int CIN, int COUT, int P>   // P*COUT == 256
__launch_bounds__(256, 2)
__global__ void edgeconv(const float* __restrict__ X, const int* __restrict__ idxb,
                         const float* __restrict__ wT, const float* __restrict__ bnp,
                         float* __restrict__ Y) {
    __shared__ float sctr[P][CIN];
    __shared__ float snb[P][KNN_K * CIN];
    int base = blockIdx.x * P;
    int tid = threadIdx.x;
    for (int j = tid; j < P * CIN; j += 256) {
        int p = j / CIN, i = j % CIN;
        sctr[p][i] = X[(size_t)(base + p) * CIN + i];
    }
    for (int j = tid; j < P * KNN_K * CIN; j += 256) {
        int p = j / (KNN_K * CIN); int r = j % (KNN_K * CIN);
        int k = r / CIN; int i = r % CIN;
        int b = (base + p) / N_;
        int ni = idxb[(size_t)(base + p) * KNN_K + k];
        snb[p][k * CIN + i] = X[((size_t)b * N_ + ni) * CIN + i];
    }
    __syncthreads();
    int p = tid / COUT, o = tid % COUT;
    float wreg[CIN];
#pragma unroll
    for (int i = 0; i < CIN; ++i) wreg[i] = wT[i * COUT + o];
    float g = bnp[o], bb = bnp[COUT + o], m = bnp[2*COUT + o], va = bnp[3*COUT + o];
    float a = g / sqrtf(va + 1e-5f);
    float sh = bb - m * a;
    float accc = 0.f;
#pragma unroll
    for (int i = 0; i < CIN; ++i)
        accc = fmaf(wT[(CIN + i) * COUT + o] - wreg[i], sctr[p][i], accc);
    float mx = -INFINITY;
    for (int k = 0; k < KNN_K; ++k) {
        float s = accc;
#pragma unroll
        for (int i = 0; i < CIN; ++i)
            s = fmaf(wreg[i], snb[p][k * CIN + i], s);
        float r = fmaf(s, a, sh);
        r = (r >= 0.f) ? r : 0.2f * r;
        mx = fmaxf(mx, r);
    }
    Y[(size_t)(base + p) * COUT + o] = mx;
}

// ---------------- lin4 (256->256->64), 4 points/block, + scatter-add --------
__launch_bounds__(256)
__global__ void k_lin4(const float* __restrict__ x1, const float* __restrict__ x2,
                       const float* __restrict__ x3, const float* __restrict__ l4a,
                       const float* __restrict__ l4b, const int* __restrict__ vbuf,
                       const int* __restrict__ ubuf, float* __restrict__ fmA) {
    int p0 = blockIdx.x * 4; int tid = threadIdx.x;
    __shared__ float xc[4][256]; __shared__ float t1s[4][256];
    for (int j = tid; j < 1024; j += 256) {
        int p = j >> 8, i = j & 255;
        int bn = p0 + p;
        float v;
        if (i < 64)       v = x1[(size_t)bn*64 + i];
        else if (i < 128) v = x2[(size_t)bn*64 + i - 64];
        else              v = x3[(size_t)bn*128 + i - 128];
        xc[p][i] = v;
    }
    __syncthreads();
    float acc[4] = {0.f, 0.f, 0.f, 0.f};
#pragma unroll 8
    for (int i = 0; i < 256; ++i) {
        float wv = l4a[i*256 + tid];
#pragma unroll
        for (int p = 0; p < 4; ++p) acc[p] = fmaf(xc[p][i], wv, acc[p]);
    }
#pragma unroll
    for (int p = 0; p < 4; ++p) t1s[p][tid] = acc[p];
    __syncthreads();
    int o = tid & 63, pg = tid >> 6;
    float a2 = 0.f;
#pragma unroll 8
    for (int i = 0; i < 256; ++i) a2 = fmaf(t1s[pg][i], l4b[i*64 + o], a2);
    int bn = p0 + pg;
    int b = bn >> 12; int v = vbuf[bn] >> 1; int u = ubuf[bn] >> 1;
    atomicAdd(fmA + ((size_t)(b*FH_ + v)*FW_ + u)*64 + o, a2);
}

// ---------------- per-pixel channel softmax ----------------
__global__ void k_softmax(float* __restrict__ fm) {
    int pix = blockIdx.x * 4 + (threadIdx.x >> 6);
    int l = threadIdx.x & 63;
    float x = fm[(size_t)pix*64 + l];
    float m = x;
    for (int off = 32; off > 0; off >>= 1) m = fmaxf(m, __shfl_xor(m, off));
    float e = expf(x - m);
    float s = e;
    for (int off = 32; off > 0; off >>= 1) s += __shfl_xor(s, off);
    fm[(size_t)pix*64 + l] = e / s;
}

// ---------------- DCN value GEMV: 8 px/block, 2 px/thread ----------------
__launch_bounds__(256)
__global__ void k_dcnval(const float* __restrict__ in, const float* __restrict__ vw,
                         const float* __restrict__ vb, float* __restrict__ val) {
    __shared__ float sx[8][64];
    int tid = threadIdx.x;
    size_t base = (size_t)blockIdx.x * 512;
    if (tid < 128) ((float4*)sx)[tid] = *((const float4*)(in + base) + tid);
    __syncthreads();
    int o = tid & 63; int pg = tid >> 6;
    float bias = vb[o];
    float a0 = 0.f, a1 = 0.f;
#pragma unroll
    for (int i4 = 0; i4 < 16; ++i4) {
        float4 x0 = *(const float4*)&sx[pg][i4*4];
        float4 x1 = *(const float4*)&sx[pg+4][i4*4];
        float w0 = vw[(i4*4+0)*64 + o], w1 = vw[(i4*4+1)*64 + o];
        float w2 = vw[(i4*4+2)*64 + o], w3 = vw[(i4*4+3)*64 + o];
        a0 = fmaf(x0.x,w0,a0); a0 = fmaf(x0.y,w1,a0); a0 = fmaf(x0.z,w2,a0); a0 = fmaf(x0.w,w3,a0);
        a1 = fmaf(x1.x,w0,a1); a1 = fmaf(x1.y,w1,a1); a1 = fmaf(x1.z,w2,a1); a1 = fmaf(x1.w,w3,a1);
    }
    val[base + (size_t)pg*64 + o]     = a0 + bias;
    val[base + (size_t)(pg+4)*64 + o] = a1 + bias;
}

// ---------------- DCN fused: 64 px/block, GEMM-structured ----------------
__launch_bounds__(256, 2)
__global__ void k_dcn64(const float* __restrict__ in, const float* __restrict__ val,
                        const float* __restrict__ ow, const float* __restrict__ ob,
                        const float* __restrict__ pwm, const float* __restrict__ pbm,
                        const float* __restrict__ bnp, float* __restrict__ out) {
    __shared__ float xT[64*68];     // xT[c][px] stride 68; reused as ssT[ch][px]
    __shared__ float wS[64*112];    // ow[c][o] padded; later pwm[c][o]
    __shared__ float som[64*112];   // som[px][o]
    __shared__ float stap[4][36][8];
    int tid = threadIdx.x;
    int blk = blockIdx.x;
    int b = blk / 1200;
    int hw0 = (blk % 1200) * 64;
    size_t pix0 = (size_t)b * (FH_*FW_) + hw0;

    // stage xT (transposed) + wS (offset weights, zero-padded to 112)
    {
        int px = tid >> 2, c0 = (tid & 3) * 16;
        const float* ip = in + (pix0 + px) * 64 + c0;
#pragma unroll
        for (int m = 0; m < 4; ++m) {
            float4 v = *(const float4*)(ip + m*4);
            int c = c0 + m*4;
            xT[(c+0)*68 + px] = v.x; xT[(c+1)*68 + px] = v.y;
            xT[(c+2)*68 + px] = v.z; xT[(c+3)*68 + px] = v.w;
        }
        for (int j = tid; j < 64*112; j += 256) {
            int c = j / 112, o = j % 112;
            wS[j] = (o < 108) ? ow[c*108 + o] : 0.f;
        }
    }
    __syncthreads();

    // phase A: som[px][o] = ob[o] + sum_c x[px][c]*ow[c][o]  (4x7 tiles)
    {
        int tx = tid & 15, ty = tid >> 4;
        float acc[4][7];
#pragma unroll
        for (int i=0;i<4;++i)
#pragma unroll
            for (int j=0;j<7;++j) acc[i][j]=0.f;
        for (int c = 0; c < 64; ++c) {
            float4 a = *(const float4*)&xT[c*68 + ty*4];
            float av[4] = {a.x,a.y,a.z,a.w};
            float bv[7];
#pragma unroll
            for (int j = 0; j < 7; ++j) bv[j] = wS[c*112 + tx + 16*j];
#pragma unroll
            for (int i=0;i<4;++i)
#pragma unroll
                for (int j=0;j<7;++j) acc[i][j] = fmaf(av[i], bv[j], acc[i][j]);
        }
#pragma unroll
        for (int j = 0; j < 7; ++j) {
            int o = tx + 16*j;
            float bias = (o < 108) ? ob[o] : 0.f;
#pragma unroll
            for (int i = 0; i < 4; ++i)
                som[(ty*4+i)*112 + o] = acc[i][j] + bias;
        }
    }
    __syncthreads();

    // restage wS <- pwm (64x64), safe: phase A reads done
    for (int m = 0; m < 4; ++m) {
        int idx = tid + 256*m;               // 1024 float4s
        int c = idx >> 4, o4 = (idx & 15) * 4;
        float4 v = *(const float4*)(pwm + c*64 + o4);
        *(float4*)&wS[c*112 + o4] = v;
    }

    // phase C: taps + sampling, wave wv handles px = wv*16 + j
    int wv = tid >> 6, lane = tid & 63;
    const float* vbp = val + (size_t)b * (FH_*FW_) * 64 + lane;
    for (int j = 0; j < 16; ++j) {
        int px = wv*16 + j;
        if (lane < 36) {
            int g = lane / 9, k = lane % 9;
            int hw = hw0 + px;
            int h = hw / FW_, w = hw % FW_;
            float lx = (float)(w + (k%3) - 1) + som[px*112 + g*27 + k*3 + 0];
            float ly = (float)(h + (k/3) - 1) + som[px*112 + g*27 + k*3 + 1];
            float msk = som[px*112 + g*27 + k*3 + 2];
            float x0f = floorf(lx), y0f = floorf(ly);
            float wx = lx - x0f, wy = ly - y0f;
            int x0 = (int)x0f, y0 = (int)y0f;
            bool xi0 = (unsigned)x0 < (unsigned)FW_, xi1 = (unsigned)(x0+1) < (unsigned)FW_;
            bool yi0 = (unsigned)y0 < (unsigned)FH_, yi1 = (unsigned)(y0+1) < (unsigned)FH_;
            int x0c = min(max(x0, 0), FW_-1), x1c = min(max(x0+1, 0), FW_-1);
            int y0c = min(max(y0, 0), FH_-1), y1c = min(max(y0+1, 0), FH_-1);
            stap[wv][lane][0] = __int_as_float((y0c*FW_ + x0c) * 64);
            stap[wv][lane][1] = __int_as_float((y0c*FW_ + x1c) * 64);
            stap[wv][lane][2] = __int_as_float((y1c*FW_ + x0c) * 64);
            stap[wv][lane][3] = __int_as_float((y1c*FW_ + x1c) * 64);
            stap[wv][lane][4] = (xi0 && yi0) ? msk*(1.f-wx)*(1.f-wy) : 0.f;
            stap[wv][lane][5] = (xi1 && yi0) ? msk*wx*(1.f-wy)       : 0.f;
            stap[wv][lane][6] = (xi0 && yi1) ? msk*(1.f-wx)*wy       : 0.f;
            stap[wv][lane][7] = (xi1 && yi1) ? msk*wx*wy             : 0.f;
        }
        __syncthreads();
        {
            int g9 = (lane >> 4) * 9;
            float acc0 = 0.f, acc1 = 0.f;
#pragma unroll
            for (int k = 0; k < 9; ++k) {
                const float* tp = stap[wv][g9 + k];
                float4 t0 = *(const float4*)tp;
                float4 t1 = *(const float4*)(tp + 4);
                float v00 = vbp[__float_as_int(t0.x)];
                float v01 = vbp[__float_as_int(t0.y)];
                float v10 = vbp[__float_as_int(t0.z)];
                float v11 = vbp[__float_as_int(t0.w)];
                acc0 = fmaf(t1.x, v00, acc0);
                acc1 = fmaf(t1.y, v01, acc1);
                acc0 = fmaf(t1.z, v10, acc0);
                acc1 = fmaf(t1.w, v11, acc1);
            }
            xT[lane*68 + px] = acc0 + acc1;   // ssT[ch][px]
        }
        __syncthreads();
    }

    // phase D: out[px][o] = bnlrelu( sum_ch ss[px][ch]*pwm[ch][o] + pbm[o] )
    {
        int tx = tid & 15, ty = tid >> 4;
        float acc[4][4];
#pragma unroll
        for (int i=0;i<4;++i)
#pragma unroll
            for (int j=0;j<4;++j) acc[i][j]=0.f;
        for (int c = 0; c < 64; ++c) {
            float4 a = *(const float4*)&xT[c*68 + ty*4];
            float4 bb = *(const float4*)&wS[c*112 + tx*4];
            float av[4] = {a.x,a.y,a.z,a.w};
            float bv[4] = {bb.x,bb.y,bb.z,bb.w};
#pragma unroll
            for (int i=0;i<4;++i)
#pragma unroll
                for (int j=0;j<4;++j) acc[i][j] = fmaf(av[i], bv[j], acc[i][j]);
        }
#pragma unroll
        for (int i = 0; i < 4; ++i) {
            int px = ty*4 + i;
            float vr[4];
#pragma unroll
            for (int jj = 0; jj < 4; ++jj) {
                int o = tx*4 + jj;
                float aa = acc[i][jj] + pbm[o];
                float g = bnp[o], be = bnp[64+o], m = bnp[128+o], va = bnp[192+o];
                float sc = g / sqrtf(va + 1e-5f);
                float r = (aa - m) * sc + be;
                vr[jj] = (r >= 0.f) ? r : 0.2f * r;
            }
            *(float4*)&out[(pix0 + px)*64 + tx*4] = make_float4(vr[0],vr[1],vr[2],vr[3]);
        }
    }
}

// ---------------- conv7a + conv7b, 16 pixels/block ----------------
__launch_bounds__(256)
__global__ void k_conv7(const float* __restrict__ in, const float* __restrict__ w7aT,
                        const float* __restrict__ w7bT, float* __restrict__ out) {
    int blk = blockIdx.x;
    int b = blk / ((FH_*FW_)/16);
    int hw0 = (blk % ((FH_*FW_)/16)) * 16;
    int tid = threadIdx.x;
    __shared__ float sx[16][64];
    __shared__ float st[16][64];
    for (int j = tid; j < 1024; j += 256) {
        int p = j >> 6, c = j & 63;
        sx[p][c] = in[((size_t)(b*(FH_*FW_) + hw0 + p))*64 + c];
    }
    __syncthreads();
    {
        int o = tid & 63, p4 = tid >> 6;
        float acc[4] = {0.f, 0.f, 0.f, 0.f};
#pragma unroll 8
        for (int c = 0; c < 64; ++c) {
            float wv = w7aT[c*64 + o];
#pragma unroll
            for (int j = 0; j < 4; ++j) acc[j] = fmaf(sx[p4*4+j][c], wv, acc[j]);
        }
#pragma unroll
        for (int j = 0; j < 4; ++j) st[p4*4+j][o] = acc[j];
    }
    __syncthreads();
    {
        int po = tid >> 1, half = tid & 1;
        float acc[8] = {0.f};
#pragma unroll 8
        for (int c = 0; c < 64; ++c) {
            float wv = w7bT[c*128 + po];
#pragma unroll
            for (int j = 0; j < 8; ++j) acc[j] = fmaf(st[half*8+j][c], wv, acc[j]);
        }
        float* op = out + ((size_t)b*128 + po)*(FH_*FW_) + hw0 + half*8;
        *(float4*)op       = make_float4(acc[0], acc[1], acc[2], acc[3]);
        *(float4*)(op + 4) = make_float4(acc[4], acc[5], acc[6], acc[7]);
    }
}

// ---------------- launch ----------------
extern "C" void kernel_launch(void* const* d_in, const int* in_sizes, int n_in,
                              void* d_out, int out_size, void* d_ws, size_t ws_size,
                              hipStream_t stream) {
    (void)in_sizes; (void)n_in; (void)out_size; (void)ws_size;
    const float* pc   = (const float*)d_in[0];
    const float* img  = (const float*)d_in[1];
    const float* pcw  = (const float*)d_in[2];
    const float* pcb  = (const float*)d_in[3];
    const float* c1w  = (const float*)d_in[4];
    const float* c1b  = (const float*)d_in[5];
    const float* cabn = (const float*)d_in[6];
    const float* chw  = (const float*)d_in[7];
    const float* chb  = (const float*)d_in[8];
    const float* cww  = (const float*)d_in[9];
    const float* cwb  = (const float*)d_in[10];
    const float* w1   = (const float*)d_in[11];
    const float* bn1  = (const float*)d_in[12];
    const float* w2   = (const float*)d_in[13];
    const float* bn2  = (const float*)d_in[14];
    const float* w3   = (const float*)d_in[15];
    const float* bn3  = (const float*)d_in[16];
    const float* l4a  = (const float*)d_in[17];
    const float* l4b  = (const float*)d_in[18];
    const float* d5ow = (const float*)d_in[19];
    const float* d5ob = (const float*)d_in[20];
    const float* d5vw = (const float*)d_in[21];
    const float* d5vb = (const float*)d_in[22];
    const float* d5pw = (const float*)d_in[23];
    const float* d5pb = (const float*)d_in[24];
    const float* bn5  = (const float*)d_in[25];
    const float* d6ow = (const float*)d_in[26];
    const float* d6ob = (const float*)d_in[27];
    const float* d6vw = (const float*)d_in[28];
    const float* d6vb = (const float*)d_in[29];
    const float* d6pw = (const float*)d_in[30];
    const float* d6pb = (const float*)d_in[31];
    const float* bn6  = (const float*)d_in[32];
    const float* w7a  = (const float*)d_in[33];
    const float* w7b  = (const float*)d_in[34];

    float* ws  = (float*)d_ws;
    float* out = (float*)d_out;

    float* rs  = ws + OFF_RS;   float* cs  = ws + OFF_CS;
    float* ph  = ws + OFF_PH;   float* pw  = ws + OFF_PW;
    float* y8  = ws + OFF_Y8;   float* ah  = ws + OFF_AH;  float* aw = ws + OFF_AW;
    int*   vb  = (int*)(ws + OFF_VB);
    int*   ub  = (int*)(ws + OFF_UB);
    float* f3d = ws + OFF_F3D;  float* xx  = ws + OFF_XX;
    int*   idxb = (int*)(ws + OFF_IDX);
    float* x1  = ws + OFF_X1;   float* x2  = ws + OFF_X2;  float* x3 = ws + OFF_X3;
    float* t1  = ws + OFF_T1;   float* t2  = ws + OFF_T2;  float* t3 = ws + OFF_T3;
    float* t7a = ws + OFF_T7A;  float* t7b = ws + OFF_T7B;
    float* fmA = ws + OFF_FMA;  float* fmV = ws + OFF_FMV; float* fmB = ws + OFF_FMB;
    float* pdb = ws + OFF_FMA;  // pd matrix reuses fmA+fmV region during KNN

    k_transpose<<<160, 256, 0, stream>>>(w1, w2, w3, w7a, w7b, t1, t2, t3, t7a, t7b);
    k_colsum<<<B_*3, W0, 0, stream>>>(img, cs);
    k_rowsum<<<B_*3, H0, 0, stream>>>(img, rs);
    k_ph<<<(B_*24*H0 + 255)/256, 256, 0, stream>>>(img, rs, pcw, pcb, ph);
    k_pw<<<(B_*24*W0 + 255)/256, 256, 0, stream>>>(img, cs, pcw, pcb, pw);
    k_y8<<<(B_*8*1120 + 255)/256, 256, 0, stream>>>(ph, pw, c1w, c1b, cabn, y8);
    k_ahw<<<(B_*24*1120 + 255)/256, 256, 0, stream>>>(y8, chw, chb, cww, cwb, ah, aw);
    k_feat3d<<<(BN_*32)/256, 256, 0, stream>>>(pc, img, pcw, pcb, ah, aw, f3d, vb, ub,
                                               out + (size_t)B_*128*FH_*FW_);

    // EdgeConv stage 1 (C=32)
    k_sqnorm<32><<<BN_/256, 256, 0, stream>>>(f3d, xx);
    for (int b = 0; b < B_; ++b) {
        k_dist<32><<<1024, 256, 0, stream>>>(f3d, xx, pdb, b);
        k_select<<<N_/4, 256, 0, stream>>>(pdb, idxb, b);
    }
    edgeconv<32,64,4><<<BN_/4, 256, 0, stream>>>(f3d, idxb, t1, bn1, x1);
    // stage 2 (C=64)
    k_sqnorm<64><<<BN_/256, 256, 0, stream>>>(x1, xx);
    for (int b = 0; b < B_; ++b) {
        k_dist<64><<<1024, 256, 0, stream>>>(x1, xx, pdb, b);
        k_select<<<N_/4, 256, 0, stream>>>(pdb, idxb, b);
    }
    edgeconv<64,64,4><<<BN_/4, 256, 0, stream>>>(x1, idxb, t2, bn2, x2);
    // stage 3 (C=64)
    k_sqnorm<64><<<BN_/256, 256, 0, stream>>>(x2, xx);
    for (int b = 0; b < B_; ++b) {
        k_dist<64><<<1024, 256, 0, stream>>>(x2, xx, pdb, b);
        k_select<<<N_/4, 256, 0, stream>>>(pdb, idxb, b);
    }
    edgeconv<64,128,2><<<BN_/2, 256, 0, stream>>>(x2, idxb, t3, bn3, x3);

    // fm pipeline (fmA/fmV free again from here)
    hipMemsetAsync(fmA, 0, (size_t)PIX_ * 64 * sizeof(float), stream);
    k_lin4<<<BN_/4, 256, 0, stream>>>(x1, x2, x3, l4a, l4b, vb, ub, fmA);
    k_softmax<<<PIX_/4, 256, 0, stream>>>(fmA);

    k_dcnval<<<PIX_/8, 256, 0, stream>>>(fmA, d5vw, d5vb, fmV);
    k_dcn64<<<PIX_/64, 256, 0, stream>>>(fmA, fmV, d5ow, d5ob, d5pw, d5pb, bn5, fmB);
    k_dcnval<<<PIX_/8, 256, 0, stream>>>(fmB, d6vw, d6vb, fmV);
    k_dcn64<<<PIX_/64, 256, 0, stream>>>(fmB, fmV, d6ow, d6ob, d6pw, d6pb, bn6, fmA);

    k_conv7<<<PIX_/16, 256, 0, stream>>>(fmA, t7a, t7b, out);
}

// Round 5
// 1856.544 us; speedup vs baseline: 2.7972x; 1.0334x over previous
//
#include <hip/hip_runtime.h>
#include <math.h>

#define B_    2
#define N_    4096
#define BN_   (B_*N_)
#define H0    480
#define W0    640
#define FH_   240
#define FW_   320
#define PIX_  (B_*FH_*FW_)     // 153600
#define KNN_K 20

// ---------------- workspace layout (float offsets) ----------------
static const size_t OFF_RS   = 0;
static const size_t OFF_CS   = 2944;
static const size_t OFF_PH   = 6784;
static const size_t OFF_PW   = 29824;
static const size_t OFF_Y8   = 60544;
static const size_t OFF_AH   = 78464;
static const size_t OFF_AW   = 101504;
static const size_t OFF_VB   = 132224;
static const size_t OFF_UB   = 140416;
static const size_t OFF_F3D  = 148608;
static const size_t OFF_XX   = 410752;
static const size_t OFF_IDX  = 5661824;
static const size_t OFF_X1   = 5825664;
static const size_t OFF_X2   = 6349952;
static const size_t OFF_X3   = 6874240;
static const size_t OFF_T1   = 7922816;
static const size_t OFF_T2   = 7926912;
static const size_t OFF_T3   = 7935104;
static const size_t OFF_T7A  = 7951488;
static const size_t OFF_T7B  = 7955584;
static const size_t OFF_FMA  = 7963776;   // pd matrix reuses fmA+fmV during KNN
static const size_t OFF_FMV  = 17794176;
static const size_t OFF_FMB  = 27624576;

// ---------------- small weight transposes ----------------
__global__ void k_transpose(const float* __restrict__ w1, const float* __restrict__ w2,
                            const float* __restrict__ w3, const float* __restrict__ w7a,
                            const float* __restrict__ w7b,
                            float* __restrict__ t1, float* __restrict__ t2,
                            float* __restrict__ t3, float* __restrict__ t7a,
                            float* __restrict__ t7b) {
    int t = blockIdx.x * 256 + threadIdx.x;
    if (t < 4096) {
        int i = t >> 6, o = t & 63; t1[i*64+o] = w1[o*64+i];
    } else if (t < 12288) {
        int r = t - 4096; int i = r >> 6, o = r & 63; t2[i*64+o] = w2[o*128+i];
    } else if (t < 28672) {
        int r = t - 12288; int i = r >> 7, o = r & 127; t3[i*128+o] = w3[o*128+i];
    } else if (t < 32768) {
        int r = t - 28672; int c = r >> 6, o = r & 63; t7a[c*64+o] = w7a[o*64+c];
    } else if (t < 40960) {
        int r = t - 32768; int o = r >> 7, p = r & 127; t7b[o*128+p] = w7b[p*64+o];
    }
}

// ---------------- input row/col sums ----------------
__global__ void k_colsum(const float* __restrict__ img, float* __restrict__ cs) {
    int bc = blockIdx.x; int x = threadIdx.x;
    const float* p = img + (size_t)bc * H0 * W0;
    float acc = 0.f;
    for (int h = 0; h < H0; ++h) acc += p[h * W0 + x];
    cs[bc * W0 + x] = acc;
}
__global__ void k_rowsum(const float* __restrict__ img, float* __restrict__ rs) {
    int bc = blockIdx.x; int y = threadIdx.x;
    const float* p = img + (size_t)bc * H0 * W0 + (size_t)y * W0;
    float acc = 0.f;
    for (int x = 0; x < W0; ++x) acc += p[x];
    rs[bc * H0 + y] = acc;
}

// ---------------- pooled conv means ph/pw ----------------
__global__ void k_ph(const float* __restrict__ img, const float* __restrict__ rs,
                     const float* __restrict__ w, const float* __restrict__ bias,
                     float* __restrict__ ph) {
    int t = blockIdx.x * 256 + threadIdx.x;
    if (t >= B_ * 24 * H0) return;
    int h = t % H0; int bc = t / H0; int c = bc % 24; int b = bc / 24;
    float acc = 0.f;
    for (int ic = 0; ic < 3; ++ic)
        for (int dy = 0; dy < 3; ++dy) {
            int y = h + dy - 1;
            if ((unsigned)y >= (unsigned)H0) continue;
            float r = rs[(b*3+ic)*H0 + y];
            const float* row = img + (size_t)((b*3+ic)*H0 + y) * W0;
            float e0 = row[0], eL = row[W0-1];
            const float* wp = w + ((c*3+ic)*3+dy)*3;
            acc += wp[0]*(r - eL) + wp[1]*r + wp[2]*(r - e0);
        }
    ph[t] = bias[c] + acc / 640.0f;
}
__global__ void k_pw(const float* __restrict__ img, const float* __restrict__ cs,
                     const float* __restrict__ w, const float* __restrict__ bias,
                     float* __restrict__ pw) {
    int t = blockIdx.x * 256 + threadIdx.x;
    if (t >= B_ * 24 * W0) return;
    int x = t % W0; int bc = t / W0; int c = bc % 24; int b = bc / 24;
    float acc = 0.f;
    for (int ic = 0; ic < 3; ++ic)
        for (int dx = 0; dx < 3; ++dx) {
            int xx = x + dx - 1;
            if ((unsigned)xx >= (unsigned)W0) continue;
            float csv = cs[(b*3+ic)*W0 + xx];
            const float* base = img + (size_t)(b*3+ic) * H0 * W0;
            float top = base[xx];
            float bot = base[(size_t)(H0-1)*W0 + xx];
            const float* wp = w + ((c*3+ic)*3)*3 + dx;
            acc += wp[0]*(csv - bot) + wp[3]*csv + wp[6]*(csv - top);
        }
    pw[t] = bias[c] + acc / 480.0f;
}

// ---------------- coord-attention mid + gates ----------------
__global__ void k_y8(const float* __restrict__ ph, const float* __restrict__ pw,
                     const float* __restrict__ c1w, const float* __restrict__ c1b,
                     const float* __restrict__ bnp, float* __restrict__ y8) {
    int t = blockIdx.x * 256 + threadIdx.x;
    if (t >= B_ * 8 * 1120) return;
    int pos = t % 1120; int bj = t / 1120; int j = bj % 8; int b = bj / 8;
    float s = c1b[j];
    for (int c = 0; c < 24; ++c) {
        float yv = (pos < H0) ? ph[(b*24+c)*H0 + pos] : pw[(b*24+c)*W0 + (pos - H0)];
        s = fmaf(c1w[j*24+c], yv, s);
    }
    float g = bnp[j], be = bnp[8+j], m = bnp[16+j], va = bnp[24+j];
    float v = (s - m) * (g / sqrtf(va + 1e-5f)) + be;
    float hs = v * fminf(fmaxf(v + 3.f, 0.f), 6.f) * (1.f/6.f);
    y8[(b*8+j)*1120 + pos] = hs;
}
__global__ void k_ahw(const float* __restrict__ y8,
                      const float* __restrict__ chw, const float* __restrict__ chb,
                      const float* __restrict__ cww, const float* __restrict__ cwb,
                      float* __restrict__ ah, float* __restrict__ aw) {
    int t = blockIdx.x * 256 + threadIdx.x;
    if (t >= B_ * 24 * 1120) return;
    int pos = t % 1120; int bc = t / 1120; int c = bc % 24; int b = bc / 24;
    if (pos < H0) {
        float s = chb[c];
        for (int j = 0; j < 8; ++j) s = fmaf(chw[c*8+j], y8[(b*8+j)*1120 + pos], s);
        ah[(b*24+c)*H0 + pos] = 1.f / (1.f + expf(-s));
    } else {
        float s = cwb[c];
        for (int j = 0; j < 8; ++j) s = fmaf(cww[c*8+j], y8[(b*8+j)*1120 + pos], s);
        aw[(b*24+c)*W0 + (pos - H0)] = 1.f / (1.f + expf(-s));
    }
}

// ---------------- feat3d gather (+v/u + idx output) ----------------
__global__ void k_feat3d(const float* __restrict__ pc, const float* __restrict__ img,
                         const float* __restrict__ w, const float* __restrict__ bias,
                         const float* __restrict__ ah, const float* __restrict__ aw,
                         float* __restrict__ f3d, int* __restrict__ vbuf,
                         int* __restrict__ ubuf, float* __restrict__ idx_out) {
    int t = blockIdx.x * 256 + threadIdx.x;
    if (t >= BN_ * 32) return;
    int c = t & 31; int bn = t >> 5; int b = bn >> 12; int n = bn & (N_-1);
    float pv = pc[(b*8 + 0)*N_ + n];
    float pu = pc[(b*8 + 1)*N_ + n];
    int v = (int)floorf(pv + 240.f);
    int u = (int)floorf(pu + 320.f);
    float f;
    if (c < 8) {
        f = pc[(b*8 + c)*N_ + n];
    } else {
        int co = c - 8;
        float acc = bias[co];
        for (int ic = 0; ic < 3; ++ic)
            for (int dy = 0; dy < 3; ++dy) {
                int y = v + dy - 1;
                if ((unsigned)y >= (unsigned)H0) continue;
                for (int dx = 0; dx < 3; ++dx) {
                    int x = u + dx - 1;
                    if ((unsigned)x >= (unsigned)W0) continue;
                    acc = fmaf(w[((co*3+ic)*3+dy)*3+dx],
                               img[((size_t)(b*3+ic)*H0 + y)*W0 + x], acc);
                }
            }
        f = acc * ah[(b*24+co)*H0 + v] * aw[(b*24+co)*W0 + u];
    }
    f3d[(size_t)bn*32 + c] = f;
    if (c == 0) {
        vbuf[bn] = v; ubuf[bn] = u;
        idx_out[bn] = (float)b;
        idx_out[BN_ + bn] = (float)(v >> 1);
        idx_out[2*BN_ + bn] = (float)(u >> 1);
    }
}

// ---------------- squared norms ----------------
template<int C>
__global__ void k_sqnorm(const float* __restrict__ X, float* __restrict__ XX) {
    int t = blockIdx.x * 256 + threadIdx.x;
    if (t >= BN_) return;
    float acc = 0.f;
    const float* p = X + (size_t)t * C;
#pragma unroll
    for (int i = 0; i < C; ++i) acc = fmaf(p[i], p[i], acc);
    XX[t] = acc;
}

// ---------------- distance matrix: 128x128 tile, 8x8 micro-tile ----------
template<int C>
__launch_bounds__(256, 2)
__global__ void k_dist(const float* __restrict__ X, const float* __restrict__ XX,
                       float* __restrict__ pd, int b) {
    __shared__ float As[C*128];
    __shared__ float Bs[C*128];
    int tid = threadIdx.x;
    int I = blockIdx.x >> 5, J = blockIdx.x & 31;
    {
        int r = tid >> 1, c0 = (tid & 1) * (C/2);
        const float* qa = X + ((size_t)(b*N_ + I*128 + r)) * C + c0;
        const float* ca = X + ((size_t)(b*N_ + J*128 + r)) * C + c0;
#pragma unroll
        for (int m = 0; m < C/8; ++m) {
            float4 va = *(const float4*)(qa + m*4);
            float4 vb = *(const float4*)(ca + m*4);
            int c = c0 + m*4;
            As[(c+0)*128+r]=va.x; As[(c+1)*128+r]=va.y; As[(c+2)*128+r]=va.z; As[(c+3)*128+r]=va.w;
            Bs[(c+0)*128+r]=vb.x; Bs[(c+1)*128+r]=vb.y; Bs[(c+2)*128+r]=vb.z; Bs[(c+3)*128+r]=vb.w;
        }
    }
    __syncthreads();
    int tx = tid & 15, ty = tid >> 4;
    float acc[8][8];
#pragma unroll
    for (int i=0;i<8;++i)
#pragma unroll
        for (int j=0;j<8;++j) acc[i][j]=0.f;
    for (int k = 0; k < C; ++k) {
        float4 a0 = *(const float4*)&As[k*128 + ty*8];
        float4 a1 = *(const float4*)&As[k*128 + ty*8 + 4];
        float4 b0 = *(const float4*)&Bs[k*128 + tx*8];
        float4 b1 = *(const float4*)&Bs[k*128 + tx*8 + 4];
        float av[8] = {a0.x,a0.y,a0.z,a0.w,a1.x,a1.y,a1.z,a1.w};
        float bv[8] = {b0.x,b0.y,b0.z,b0.w,b1.x,b1.y,b1.z,b1.w};
#pragma unroll
        for (int i = 0; i < 8; ++i)
#pragma unroll
            for (int j = 0; j < 8; ++j)
                acc[i][j] = fmaf(av[i], bv[j], acc[i][j]);
    }
    float xq[8], xc[8];
#pragma unroll
    for (int i = 0; i < 8; ++i) {
        xq[i] = XX[b*N_ + I*128 + ty*8 + i];
        xc[i] = XX[b*N_ + J*128 + tx*8 + i];
    }
#pragma unroll
    for (int i = 0; i < 8; ++i) {
        int row = I*128 + ty*8 + i;
        float4 o0, o1;
        o0.x = 2.f*acc[i][0] - xq[i] - xc[0]; o0.y = 2.f*acc[i][1] - xq[i] - xc[1];
        o0.z = 2.f*acc[i][2] - xq[i] - xc[2]; o0.w = 2.f*acc[i][3] - xq[i] - xc[3];
        o1.x = 2.f*acc[i][4] - xq[i] - xc[4]; o1.y = 2.f*acc[i][5] - xq[i] - xc[5];
        o1.z = 2.f*acc[i][6] - xq[i] - xc[6]; o1.w = 2.f*acc[i][7] - xq[i] - xc[7];
        *(float4*)&pd[(size_t)row*N_ + J*128 + tx*8]     = o0;
        *(float4*)&pd[(size_t)row*N_ + J*128 + tx*8 + 4] = o1;
    }
}

// ---------------- wave-per-query top-20 ----------------
__launch_bounds__(256)
__global__ void k_select(const float* __restrict__ pd, int* __restrict__ idxb, int b) {
    int wv = threadIdx.x >> 6, lane = threadIdx.x & 63;
    int q = blockIdx.x * 4 + wv;
    const float* row = pd + (size_t)q * N_;
    float val[12]; int idx[12];
#pragma unroll
    for (int j = 0; j < 12; ++j) { val[j] = -INFINITY; idx[j] = 0x7fffffff; }
    for (int t = 0; t < N_ / 256; ++t) {
        float4 v4 = *(const float4*)(row + t * 256 + lane * 4);
        float vv[4] = {v4.x, v4.y, v4.z, v4.w};
#pragma unroll
        for (int j = 0; j < 4; ++j) {
            float v = vv[j];
            if (v > val[11]) {
                float cv = v; int cc = t * 256 + lane * 4 + j; bool ins = false;
#pragma unroll
                for (int s = 0; s < 12; ++s) {
                    bool sw = ins || (cv > val[s]);
                    if (sw) {
                        float tv = val[s]; val[s] = cv; cv = tv;
                        int ti = idx[s]; idx[s] = cc; cc = ti;
                        ins = true;
                    }
                }
            }
        }
    }
    int nb = 0;
    float hv = val[0]; int hi = idx[0];
#pragma unroll 1
    for (int slot = 0; slot < KNN_K; ++slot) {
        float wvv = hv; int wi = hi; int wl = lane;
#pragma unroll
        for (int off = 1; off < 64; off <<= 1) {
            float ov = __shfl_xor(wvv, off);
            int   oi = __shfl_xor(wi, off);
            int   ol = __shfl_xor(wl, off);
            bool take = (ov > wvv) || (ov == wvv && oi < wi);
            if (take) { wvv = ov; wi = oi; wl = ol; }
        }
        if (lane == slot) nb = wi;
        bool pop = (lane == wl);
#pragma unroll
        for (int s = 0; s < 11; ++s)
            if (pop) { val[s] = val[s+1]; idx[s] = idx[s+1]; }
        if (pop) { val[11] = -INFINITY; idx[11] = 0x7fffffff; }
        hv = val[0]; hi = idx[0];
    }
    if (lane < KNN_K) idxb[(size_t)(b * N_ + q) * KNN_K + lane] = nb;
}

// ---------------- EdgeConv: float4 LDS + hoisted weights ----------------
template<int CIN, int COUT, int P>   // P*COUT == 256
__launch_bounds__(256, 2)
__global__ void edgeconv(const float* __restrict__ X, const int* __restrict__ idxb,
                         const float* __restrict__ wT, const float* __restrict__ bnp,
                         float* __restrict__ Y) {
    __shared__ float sctr[P][CIN];
    __shared__ float snb[P][KNN_K * CIN];
    int base = blockIdx.x * P;
    int tid = threadIdx.x;
    const int CIN4 = CIN / 4;
    if (tid < P * CIN4) {
        int p = tid / CIN4, i4 = tid % CIN4;
        ((float4*)sctr[p])[i4] = ((const float4*)&X[(size_t)(base + p) * CIN])[i4];
    }
    for (int j = tid; j < P * KNN_K * CIN4; j += 256) {
        int r = j / CIN4, i4 = j % CIN4;
        int p = r / KNN_K, k = r % KNN_K;
        int b = (base + p) / N_;
        int ni = idxb[(size_t)(base + p) * KNN_K + k];
        ((float4*)snb[p])[k * CIN4 + i4] =
            ((const float4*)&X[((size_t)b * N_ + ni) * CIN])[i4];
    }
    __syncthreads();
    int p = tid / COUT, o = tid % COUT;
    float wreg[CIN];
#pragma unroll
    for (int i = 0; i < CIN; ++i) wreg[i] = wT[i * COUT + o];
    float g = bnp[o], bb = bnp[COUT + o], m = bnp[2*COUT + o], va = bnp[3*COUT + o];
    float a = g / sqrtf(va + 1e-5f);
    float sh = bb - m * a;
    float accc = 0.f;
#pragma unroll
    for (int i = 0; i < CIN; ++i)
        accc = fmaf(wT[(CIN + i) * COUT + o] - wreg[i], sctr[p][i], accc);
    float mx = -INFINITY;
    for (int k = 0; k < KNN_K; ++k) {
        const float4* nb4 = (const float4*)&snb[p][k * CIN];
        float s = accc;
#pragma unroll
        for (int i4 = 0; i4 < CIN4; ++i4) {
            float4 v = nb4[i4];
            s = fmaf(wreg[4*i4+0], v.x, s);
            s = fmaf(wreg[4*i4+1], v.y, s);
            s = fmaf(wreg[4*i4+2], v.z, s);
            s = fmaf(wreg[4*i4+3], v.w, s);
        }
        float r = fmaf(s, a, sh);
        r = (r >= 0.f) ? r : 0.2f * r;
        mx = fmaxf(mx, r);
    }
    Y[(size_t)(base + p) * COUT + o] = mx;
}

// ---------------- lin4 (256->256->64), 4 points/block, + scatter-add --------
__launch_bounds__(256)
__global__ void k_lin4(const float* __restrict__ x1, const float* __restrict__ x2,
                       const float* __restrict__ x3, const float* __restrict__ l4a,
                       const float* __restrict__ l4b, const int* __restrict__ vbuf,
                       const int* __restrict__ ubuf, float* __restrict__ fmA) {
    int p0 = blockIdx.x * 4; int tid = threadIdx.x;
    __shared__ float xc[4][256]; __shared__ float t1s[4][256];
    for (int j = tid; j < 1024; j += 256) {
        int p = j >> 8, i = j & 255;
        int bn = p0 + p;
        float v;
        if (i < 64)       v = x1[(size_t)bn*64 + i];
        else if (i < 128) v = x2[(size_t)bn*64 + i - 64];
        else              v = x3[(size_t)bn*128 + i - 128];
        xc[p][i] = v;
    }
    __syncthreads();
    float acc[4] = {0.f, 0.f, 0.f, 0.f};
#pragma unroll 8
    for (int i = 0; i < 256; ++i) {
        float wv = l4a[i*256 + tid];
#pragma unroll
        for (int p = 0; p < 4; ++p) acc[p] = fmaf(xc[p][i], wv, acc[p]);
    }
#pragma unroll
    for (int p = 0; p < 4; ++p) t1s[p][tid] = acc[p];
    __syncthreads();
    int o = tid & 63, pg = tid >> 6;
    float a2 = 0.f;
#pragma unroll 8
    for (int i = 0; i < 256; ++i) a2 = fmaf(t1s[pg][i], l4b[i*64 + o], a2);
    int bn = p0 + pg;
    int b = bn >> 12; int v = vbuf[bn] >> 1; int u = ubuf[bn] >> 1;
    atomicAdd(fmA + ((size_t)(b*FH_ + v)*FW_ + u)*64 + o, a2);
}

// ---------------- per-pixel channel softmax ----------------
__global__ void k_softmax(float* __restrict__ fm) {
    int pix = blockIdx.x * 4 + (threadIdx.x >> 6);
    int l = threadIdx.x & 63;
    float x = fm[(size_t)pix*64 + l];
    float m = x;
    for (int off = 32; off > 0; off >>= 1) m = fmaxf(m, __shfl_xor(m, off));
    float e = expf(x - m);
    float s = e;
    for (int off = 32; off > 0; off >>= 1) s += __shfl_xor(s, off);
    fm[(size_t)pix*64 + l] = e / s;
}

// ---------------- DCN value GEMV: 8 px/block, 2 px/thread ----------------
__launch_bounds__(256)
__global__ void k_dcnval(const float* __restrict__ in, const float* __restrict__ vw,
                         const float* __restrict__ vb, float* __restrict__ val) {
    __shared__ float sx[8][64];
    int tid = threadIdx.x;
    size_t base = (size_t)blockIdx.x * 512;
    if (tid < 128) ((float4*)sx)[tid] = *((const float4*)(in + base) + tid);
    __syncthreads();
    int o = tid & 63; int pg = tid >> 6;
    float bias = vb[o];
    float a0 = 0.f, a1 = 0.f;
#pragma unroll
    for (int i4 = 0; i4 < 16; ++i4) {
        float4 x0 = *(const float4*)&sx[pg][i4*4];
        float4 x1 = *(const float4*)&sx[pg+4][i4*4];
        float w0 = vw[(i4*4+0)*64 + o], w1 = vw[(i4*4+1)*64 + o];
        float w2 = vw[(i4*4+2)*64 + o], w3 = vw[(i4*4+3)*64 + o];
        a0 = fmaf(x0.x,w0,a0); a0 = fmaf(x0.y,w1,a0); a0 = fmaf(x0.z,w2,a0); a0 = fmaf(x0.w,w3,a0);
        a1 = fmaf(x1.x,w0,a1); a1 = fmaf(x1.y,w1,a1); a1 = fmaf(x1.z,w2,a1); a1 = fmaf(x1.w,w3,a1);
    }
    val[base + (size_t)pg*64 + o]     = a0 + bias;
    val[base + (size_t)(pg+4)*64 + o] = a1 + bias;
}

// ---------------- DCN fused: 64 px/block, barrier-free sampling loop ------
// Dataflow is wave-aligned: wave w owns px [16w,16w+16) in xT columns, som
// rows, and stapS[.][w][.]; all j-loop dependencies are intra-wave (lockstep
// + in-order LDS), so no block barriers inside the loop.
__launch_bounds__(256, 2)
__global__ void k_dcn64(const float* __restrict__ in, const float* __restrict__ val,
                        const float* __restrict__ ow, const float* __restrict__ ob,
                        const float* __restrict__ pwm, const float* __restrict__ pbm,
                        const float* __restrict__ bnp, float* __restrict__ out) {
    __shared__ float xT[64*68];       // xT[c][px] stride 68; reused as ssT[ch][px]
    __shared__ float wS[64*112];      // ow padded to 112; later pwm
    __shared__ float som[64*113];     // som[px][o], stride 113 (odd: no bank clash)
    __shared__ float stapS[8][4][40]; // [field][wave][tap] SoA, conflict-free
    int tid = threadIdx.x;
    int blk = blockIdx.x;
    int b = blk / 1200;
    int hw0 = (blk % 1200) * 64;
    size_t pix0 = (size_t)b * (FH_*FW_) + hw0;

    {   // stage xT (wave w stages px 16w..16w+15) + wS
        int px = tid >> 2, c0 = (tid & 3) * 16;
        const float* ip = in + (pix0 + px) * 64 + c0;
#pragma unroll
        for (int m = 0; m < 4; ++m) {
            float4 v = *(const float4*)(ip + m*4);
            int c = c0 + m*4;
            xT[(c+0)*68 + px] = v.x; xT[(c+1)*68 + px] = v.y;
            xT[(c+2)*68 + px] = v.z; xT[(c+3)*68 + px] = v.w;
        }
        for (int j = tid; j < 64*112; j += 256) {
            int c = j / 112, o = j % 112;
            wS[j] = (o < 108) ? ow[c*108 + o] : 0.f;
        }
    }
    __syncthreads();

    // phase A: som[px][o] = ob[o] + sum_c x[px][c]*ow[c][o]  (4x7 tiles)
    {
        int tx = tid & 15, ty = tid >> 4;
        float acc[4][7];
#pragma unroll
        for (int i=0;i<4;++i)
#pragma unroll
            for (int j=0;j<7;++j) acc[i][j]=0.f;
        for (int c = 0; c < 64; ++c) {
            float4 a = *(const float4*)&xT[c*68 + ty*4];
            float av[4] = {a.x,a.y,a.z,a.w};
            float bv[7];
#pragma unroll
            for (int j = 0; j < 7; ++j) bv[j] = wS[c*112 + tx + 16*j];
#pragma unroll
            for (int i=0;i<4;++i)
#pragma unroll
                for (int j=0;j<7;++j) acc[i][j] = fmaf(av[i], bv[j], acc[i][j]);
        }
#pragma unroll
        for (int j = 0; j < 7; ++j) {
            int o = tx + 16*j;
            float bias = (o < 108) ? ob[o] : 0.f;
#pragma unroll
            for (int i = 0; i < 4; ++i)
                som[(ty*4+i)*113 + o] = acc[i][j] + bias;
        }
    }
    __syncthreads();          // all waves done reading wS (phase A)

    // restage wS <- pwm (64x64)
    for (int m = 0; m < 4; ++m) {
        int idx = tid + 256*m;
        int c = idx >> 4, o4 = (idx & 15) * 4;
        float4 v = *(const float4*)(pwm + c*64 + o4);
        *(float4*)&wS[c*112 + o4] = v;
    }
    __syncthreads();          // restage visible before any wave reaches phase D

    // phase C: taps + sampling, barrier-free (intra-wave only)
    int wv = tid >> 6, lane = tid & 63;
    const float* vbp = val + (size_t)b * (FH_*FW_) * 64 + lane;
    for (int j = 0; j < 16; ++j) {
        int px = wv*16 + j;
        if (lane < 36) {
            int g = lane / 9, k = lane % 9;
            int hw = hw0 + px;
            int h = hw / FW_, w = hw % FW_;
            float lx = (float)(w + (k%3) - 1) + som[px*113 + g*27 + k*3 + 0];
            float ly = (float)(h + (k/3) - 1) + som[px*113 + g*27 + k*3 + 1];
            float msk = som[px*113 + g*27 + k*3 + 2];
            float x0f = floorf(lx), y0f = floorf(ly);
            float wx = lx - x0f, wy = ly - y0f;
            int x0 = (int)x0f, y0 = (int)y0f;
            bool xi0 = (unsigned)x0 < (unsigned)FW_, xi1 = (unsigned)(x0+1) < (unsigned)FW_;
            bool yi0 = (unsigned)y0 < (unsigned)FH_, yi1 = (unsigned)(y0+1) < (unsigned)FH_;
            int x0c = min(max(x0, 0), FW_-1), x1c = min(max(x0+1, 0), FW_-1);
            int y0c = min(max(y0, 0), FH_-1), y1c = min(max(y0+1, 0), FH_-1);
            stapS[0][wv][lane] = __int_as_float((y0c*FW_ + x0c) * 64);
            stapS[1][wv][lane] = __int_as_float((y0c*FW_ + x1c) * 64);
            stapS[2][wv][lane] = __int_as_float((y1c*FW_ + x0c) * 64);
            stapS[3][wv][lane] = __int_as_float((y1c*FW_ + x1c) * 64);
            stapS[4][wv][lane] = (xi0 && yi0) ? msk*(1.f-wx)*(1.f-wy) : 0.f;
            stapS[5][wv][lane] = (xi1 && yi0) ? msk*wx*(1.f-wy)       : 0.f;
            stapS[6][wv][lane] = (xi0 && yi1) ? msk*(1.f-wx)*wy       : 0.f;
            stapS[7][wv][lane] = (xi1 && yi1) ? msk*wx*wy             : 0.f;
        }
        __builtin_amdgcn_wave_barrier();
        {
            int g9 = (lane >> 4) * 9;
            float acc0 = 0.f, acc1 = 0.f;
#pragma unroll
            for (int k = 0; k < 9; ++k) {
                int tp = g9 + k;
                int a00 = __float_as_int(stapS[0][wv][tp]);
                int a01 = __float_as_int(stapS[1][wv][tp]);
                int a10 = __float_as_int(stapS[2][wv][tp]);
                int a11 = __float_as_int(stapS[3][wv][tp]);
                float w00 = stapS[4][wv][tp], w01 = stapS[5][wv][tp];
                float w10 = stapS[6][wv][tp], w11 = stapS[7][wv][tp];
                float v00 = vbp[a00], v01 = vbp[a01], v10 = vbp[a10], v11 = vbp[a11];
                acc0 = fmaf(w00, v00, acc0);
                acc1 = fmaf(w01, v01, acc1);
                acc0 = fmaf(w10, v10, acc0);
                acc1 = fmaf(w11, v11, acc1);
            }
            xT[lane*68 + px] = acc0 + acc1;   // ssT[ch][px], own-wave column
        }
        __builtin_amdgcn_wave_barrier();
    }
    __builtin_amdgcn_wave_barrier();

    // phase D: out[px][o] = bnlrelu( sum_ch ss[px][ch]*pwm[ch][o] + pbm[o] )
    {
        int tx = tid & 15, ty = tid >> 4;
        float acc[4][4];
#pragma unroll
        for (int i=0;i<4;++i)
#pragma unroll
            for (int j=0;j<4;++j) acc[i][j]=0.f;
        for (int c = 0; c < 64; ++c) {
            float4 a = *(const float4*)&xT[c*68 + ty*4];
            float4 bb = *(const float4*)&wS[c*112 + tx*4];
            float av[4] = {a.x,a.y,a.z,a.w};
            float bv[4] = {bb.x,bb.y,bb.z,bb.w};
#pragma unroll
            for (int i=0;i<4;++i)
#pragma unroll
                for (int j=0;j<4;++j) acc[i][j] = fmaf(av[i], bv[j], acc[i][j]);
        }
#pragma unroll
        for (int i = 0; i < 4; ++i) {
            int px = ty*4 + i;
            float vr[4];
#pragma unroll
            for (int jj = 0; jj < 4; ++jj) {
                int o = tx*4 + jj;
                float aa = acc[i][jj] + pbm[o];
                float g = bnp[o], be = bnp[64+o], m = bnp[128+o], va = bnp[192+o];
                float sc = g / sqrtf(va + 1e-5f);
                float r = (aa - m) * sc + be;
                vr[jj] = (r >= 0.f) ? r : 0.2f * r;
            }
            *(float4*)&out[(pix0 + px)*64 + tx*4] = make_float4(vr[0],vr[1],vr[2],vr[3]);
        }
    }
}

// ---------------- conv7a + conv7b, 16 pixels/block ----------------
__launch_bounds__(256)
__global__ void k_conv7(const float* __restrict__ in, const float* __restrict__ w7aT,
                        const float* __restrict__ w7bT, float* __restrict__ out) {
    int blk = blockIdx.x;
    int b = blk / ((FH_*FW_)/16);
    int hw0 = (blk % ((FH_*FW_)/16)) * 16;
    int tid = threadIdx.x;
    __shared__ float sx[16][64];
    __shared__ float st[16][64];
    for (int j = tid; j < 1024; j += 256) {
        int p = j >> 6, c = j & 63;
        sx[p][c] = in[((size_t)(b*(FH_*FW_) + hw0 + p))*64 + c];
    }
    __syncthreads();
    {
        int o = tid & 63, p4 = tid >> 6;
        float acc[4] = {0.f, 0.f, 0.f, 0.f};
#pragma unroll 8
        for (int c = 0; c < 64; ++c) {
            float wv = w7aT[c*64 + o];
#pragma unroll
            for (int j = 0; j < 4; ++j) acc[j] = fmaf(sx[p4*4+j][c], wv, acc[j]);
        }
#pragma unroll
        for (int j = 0; j < 4; ++j) st[p4*4+j][o] = acc[j];
    }
    __syncthreads();
    {
        int po = tid >> 1, half = tid & 1;
        float acc[8] = {0.f};
#pragma unroll 8
        for (int c = 0; c < 64; ++c) {
            float wv = w7bT[c*128 + po];
#pragma unroll
            for (int j = 0; j < 8; ++j) acc[j] = fmaf(st[half*8+j][c], wv, acc[j]);
        }
        float* op = out + ((size_t)b*128 + po)*(FH_*FW_) + hw0 + half*8;
        *(float4*)op       = make_float4(acc[0], acc[1], acc[2], acc[3]);
        *(float4*)(op + 4) = make_float4(acc[4], acc[5], acc[6], acc[7]);
    }
}

// ---------------- launch ----------------
extern "C" void kernel_launch(void* const* d_in, const int* in_sizes, int n_in,
                              void* d_out, int out_size, void* d_ws, size_t ws_size,
                              hipStream_t stream) {
    (void)in_sizes; (void)n_in; (void)out_size; (void)ws_size;
    const float* pc   = (const float*)d_in[0];
    const float* img  = (const float*)d_in[1];
    const float* pcw  = (const float*)d_in[2];
    const float* pcb  = (const float*)d_in[3];
    const float* c1w  = (const float*)d_in[4];
    const float* c1b  = (const float*)d_in[5];
    const float* cabn = (const float*)d_in[6];
    const float* chw  = (const float*)d_in[7];
    const float* chb  = (const float*)d_in[8];
    const float* cww  = (const float*)d_in[9];
    const float* cwb  = (const float*)d_in[10];
    const float* w1   = (const float*)d_in[11];
    const float* bn1  = (const float*)d_in[12];
    const float* w2   = (const float*)d_in[13];
    const float* bn2  = (const float*)d_in[14];
    const float* w3   = (const float*)d_in[15];
    const float* bn3  = (const float*)d_in[16];
    const float* l4a  = (const float*)d_in[17];
    const float* l4b  = (const float*)d_in[18];
    const float* d5ow = (const float*)d_in[19];
    const float* d5ob = (const float*)d_in[20];
    const float* d5vw = (const float*)d_in[21];
    const float* d5vb = (const float*)d_in[22];
    const float* d5pw = (const float*)d_in[23];
    const float* d5pb = (const float*)d_in[24];
    const float* bn5  = (const float*)d_in[25];
    const float* d6ow = (const float*)d_in[26];
    const float* d6ob = (const float*)d_in[27];
    const float* d6vw = (const float*)d_in[28];
    const float* d6vb = (const float*)d_in[29];
    const float* d6pw = (const float*)d_in[30];
    const float* d6pb = (const float*)d_in[31];
    const float* bn6  = (const float*)d_in[32];
    const float* w7a  = (const float*)d_in[33];
    const float* w7b  = (const float*)d_in[34];

    float* ws  = (float*)d_ws;
    float* out = (float*)d_out;

    float* rs  = ws + OFF_RS;   float* cs  = ws + OFF_CS;
    float* ph  = ws + OFF_PH;   float* pw  = ws + OFF_PW;
    float* y8  = ws + OFF_Y8;   float* ah  = ws + OFF_AH;  float* aw = ws + OFF_AW;
    int*   vb  = (int*)(ws + OFF_VB);
    int*   ub  = (int*)(ws + OFF_UB);
    float* f3d = ws + OFF_F3D;  float* xx  = ws + OFF_XX;
    int*   idxb = (int*)(ws + OFF_IDX);
    float* x1  = ws + OFF_X1;   float* x2  = ws + OFF_X2;  float* x3 = ws + OFF_X3;
    float* t1  = ws + OFF_T1;   float* t2  = ws + OFF_T2;  float* t3 = ws + OFF_T3;
    float* t7a = ws + OFF_T7A;  float* t7b = ws + OFF_T7B;
    float* fmA = ws + OFF_FMA;  float* fmV = ws + OFF_FMV; float* fmB = ws + OFF_FMB;
    float* pdb = ws + OFF_FMA;  // pd matrix reuses fmA+fmV region during KNN

    k_transpose<<<160, 256, 0, stream>>>(w1, w2, w3, w7a, w7b, t1, t2, t3, t7a, t7b);
    k_colsum<<<B_*3, W0, 0, stream>>>(img, cs);
    k_rowsum<<<B_*3, H0, 0, stream>>>(img, rs);
    k_ph<<<(B_*24*H0 + 255)/256, 256, 0, stream>>>(img, rs, pcw, pcb, ph);
    k_pw<<<(B_*24*W0 + 255)/256, 256, 0, stream>>>(img, cs, pcw, pcb, pw);
    k_y8<<<(B_*8*1120 + 255)/256, 256, 0, stream>>>(ph, pw, c1w, c1b, cabn, y8);
    k_ahw<<<(B_*24*1120 + 255)/256, 256, 0, stream>>>(y8, chw, chb, cww, cwb, ah, aw);
    k_feat3d<<<(BN_*32)/256, 256, 0, stream>>>(pc, img, pcw, pcb, ah, aw, f3d, vb, ub,
                                               out + (size_t)B_*128*FH_*FW_);

    // EdgeConv stage 1 (C=32)
    k_sqnorm<32><<<BN_/256, 256, 0, stream>>>(f3d, xx);
    for (int b = 0; b < B_; ++b) {
        k_dist<32><<<1024, 256, 0, stream>>>(f3d, xx, pdb, b);
        k_select<<<N_/4, 256, 0, stream>>>(pdb, idxb, b);
    }
    edgeconv<32,64,4><<<BN_/4, 256, 0, stream>>>(f3d, idxb, t1, bn1, x1);
    // stage 2 (C=64)
    k_sqnorm<64><<<BN_/256, 256, 0, stream>>>(x1, xx);
    for (int b = 0; b < B_; ++b) {
        k_dist<64><<<1024, 256, 0, stream>>>(x1, xx, pdb, b);
        k_select<<<N_/4, 256, 0, stream>>>(pdb, idxb, b);
    }
    edgeconv<64,64,4><<<BN_/4, 256, 0, stream>>>(x1, idxb, t2, bn2, x2);
    // stage 3 (C=64)
    k_sqnorm<64><<<BN_/256, 256, 0, stream>>>(x2, xx);
    for (int b = 0; b < B_; ++b) {
        k_dist<64><<<1024, 256, 0, stream>>>(x2, xx, pdb, b);
        k_select<<<N_/4, 256, 0, stream>>>(pdb, idxb, b);
    }
    edgeconv<64,128,2><<<BN_/2, 256, 0, stream>>>(x2, idxb, t3, bn3, x3);

    // fm pipeline (fmA/fmV free again from here)
    hipMemsetAsync(fmA, 0, (size_t)PIX_ * 64 * sizeof(float), stream);
    k_lin4<<<BN_/4, 256, 0, stream>>>(x1, x2, x3, l4a, l4b, vb, ub, fmA);
    k_softmax<<<PIX_/4, 256, 0, stream>>>(fmA);

    k_dcnval<<<PIX_/8, 256, 0, stream>>>(fmA, d5vw, d5vb, fmV);
    k_dcn64<<<PIX_/64, 256, 0, stream>>>(fmA, fmV, d5ow, d5ob, d5pw, d5pb, bn5, fmB);
    k_dcnval<<<PIX_/8, 256, 0, stream>>>(fmB, d6vw, d6vb, fmV);
    k_dcn64<<<PIX_/64, 256, 0, stream>>>(fmB, fmV, d6ow, d6ob, d6pw, d6pb, bn6, fmA);

    k_conv7<<<PIX_/16, 256, 0, stream>>>(fmA, t7a, t7b, out);
}